// Round 4
// baseline (819.304 us; speedup 1.0000x reference)
//
#include <hip/hip_runtime.h>
#include <hip/hip_bf16.h>

// Performer (FAVOR+) causal linear self-attention, MI355X round 3.
// B=4 L=4096 E=512 H=8 D=64 M=256 chunk=128.
// Round 3: CC=128 cattn (4x occupancy), fused chunk-scan (KV sums + transpose +
// exclusive prefix in one kernel), bf16 transform outputs + precomputed rowsums.

#define BB 4
#define LL 4096
#define EE 512
#define HH 8
#define DD 64
#define MM 256
#define CC 128
#define NCH 32   // L / CC
#define BHN 32   // B * H

constexpr float DN    = 0.35355339059327373f; // 64^-0.25
constexpr float DIAGC = 0.0625f;              // 0.5 * dn^2
constexpr float RATIO = 0.0625f;              // 256^-0.5
constexpr float EPSV  = 1e-4f;

typedef __attribute__((ext_vector_type(8))) short bf16x8;
typedef __attribute__((ext_vector_type(4))) float f32x4;
union FU { uint4 u; bf16x8 b; };
__device__ __forceinline__ bf16x8 asb(uint4 u){ FU f; f.u = u; return f.b; }
union PK2 { ushort4 s; uint2 u; };
union PK8 { unsigned short s[8]; uint4 u; };

__device__ __forceinline__ unsigned short f2bf(float f){
  unsigned u = __float_as_uint(f);
  u = u + 0x7FFFu + ((u >> 16) & 1u);   // RTNE
  return (unsigned short)(u >> 16);
}
__device__ __forceinline__ unsigned enc_f32(float f){
  unsigned u = __float_as_uint(f);
  return (u & 0x80000000u) ? ~u : (u | 0x80000000u);
}
__device__ __forceinline__ float dec_f32(unsigned u){
  unsigned v = (u & 0x80000000u) ? (u & 0x7FFFFFFFu) : ~u;
  return __uint_as_float(v);
}
__device__ __forceinline__ uint4 pack8(float4 a, float4 b){
  PK8 p;
  p.s[0] = f2bf(a.x); p.s[1] = f2bf(a.y); p.s[2] = f2bf(a.z); p.s[3] = f2bf(a.w);
  p.s[4] = f2bf(b.x); p.s[5] = f2bf(b.y); p.s[6] = f2bf(b.z); p.s[7] = f2bf(b.w);
  return p.u;
}

// ---------------- K1: head-split + DxD projection -> bf16 out + rowsum(out^2) ----------------
__global__ __launch_bounds__(256) void k_transform_b(const float* __restrict__ x,
                                                     const float* __restrict__ W,
                                                     unsigned short* __restrict__ xb,
                                                     float* __restrict__ rs){
  __shared__ float Wt[DD * 65];   // Wt[dp*65+d] = W[d][dp]
  __shared__ float xr[4][DD];
  int tid = threadIdx.x;
  for (int i = tid; i < DD * DD; i += 256){
    int d = i >> 6, dp = i & 63;
    Wt[dp * 65 + d] = W[i];
  }
  int bh = blockIdx.x >> 10;
  int l0 = (blockIdx.x & 1023) << 2;
  int b = bh >> 3, h = bh & 7;
  int r = tid >> 6, d = tid & 63;
  xr[r][d] = x[((size_t)(b * LL + l0 + r)) * EE + h * DD + d];
  __syncthreads();
  float acc = 0.f;
  #pragma unroll
  for (int dp = 0; dp < DD; ++dp)
    acc += xr[r][dp] * Wt[dp * 65 + d];
  size_t row = (size_t)bh * LL + l0 + r;
  float sq = acc * acc;
  #pragma unroll
  for (int off = 32; off >= 1; off >>= 1)
    sq += __shfl_xor(sq, off, 64);
  if (d == 0) rs[row] = sq;
  float other = __shfl_xor(acc, 1, 64);
  if ((d & 1) == 0){
    unsigned u = (unsigned)f2bf(acc) | ((unsigned)f2bf(other) << 16);
    reinterpret_cast<unsigned*>(xb)[row * 32 + (d >> 1)] = u;
  }
}

// ---------------- K1v: v transform -> transposed bf16 vT [BH][D][L] ----------------
__global__ __launch_bounds__(256) void k_transform_vT(const float* __restrict__ x,
                                                      const float* __restrict__ W,
                                                      unsigned short* __restrict__ vTb){
  __shared__ float Wt[DD * 65];
  __shared__ float T[64 * 65];
  int tid = threadIdx.x;
  for (int i = tid; i < DD * DD; i += 256){
    int d = i >> 6, dp = i & 63;
    Wt[dp * 65 + d] = W[i];
  }
  __syncthreads();
  int bh = blockIdx.x >> 6;               // grid = BH * (L/64)
  int l0 = (blockIdx.x & 63) << 6;
  int b = bh >> 3, h = bh & 7;
  int r = tid >> 6, lane = tid & 63;
  for (int g = 0; g < 16; ++g){
    int l = g * 4 + r;
    float xv = x[((size_t)(b * LL + l0 + l)) * EE + h * DD + lane];
    float acc = 0.f;
    #pragma unroll
    for (int dp = 0; dp < DD; ++dp)
      acc += __shfl(xv, dp, 64) * Wt[dp * 65 + lane];
    T[l * 65 + lane] = acc;
  }
  __syncthreads();
  int dd = tid >> 2, e0 = (tid & 3) << 4;
  PK8 p0, p1;
  #pragma unroll
  for (int jj = 0; jj < 8; ++jj){
    p0.s[jj] = f2bf(T[(e0 + jj) * 65 + dd]);
    p1.s[jj] = f2bf(T[(e0 + 8 + jj) * 65 + dd]);
  }
  uint4* op = reinterpret_cast<uint4*>(vTb + ((size_t)(bh * DD + dd)) * LL + l0 + e0);
  op[0] = p0.u;
  op[1] = p1.u;
}

// ---------------- K2: MFMA phi / kmax (bf16 inputs + precomputed rowsum) ----------------
// mode 0: global max of xd(k) -> atomicMax. mode 1: query phi. mode 2: key phi.
__global__ __launch_bounds__(256) void k_phiM(const unsigned short* __restrict__ xb,
                                              const float* __restrict__ rs,
                                              const float* __restrict__ proj,
                                              unsigned* __restrict__ kmaxp,
                                              unsigned short* __restrict__ phi,
                                              int mode){
  __shared__ unsigned short Pl[256 * 64];   // swizzled bf16 dn*proj, 32 KiB
  int tid = threadIdx.x;
  const float4* proj4 = reinterpret_cast<const float4*>(proj);
  for (int idx = tid; idx < 2048; idx += 256){
    int m = idx >> 3, c = idx & 7;
    float4 a = proj4[m * 16 + c * 2];
    float4 b = proj4[m * 16 + c * 2 + 1];
    a.x *= DN; a.y *= DN; a.z *= DN; a.w *= DN;
    b.x *= DN; b.y *= DN; b.z *= DN; b.w *= DN;
    int byte = m * 128 + ((c * 16) ^ ((m & 7) << 4));
    *reinterpret_cast<uint4*>(reinterpret_cast<char*>(Pl) + byte) = pack8(a, b);
  }
  __syncthreads();
  int w = tid >> 6, lane = tid & 63, l15 = lane & 15, g = lane >> 4;
  const uint4* xb4 = reinterpret_cast<const uint4*>(xb);
  float gm = (mode == 2) ? dec_f32(*kmaxp) : 0.f;
  int rb = blockIdx.x * 4 + w;              // grid 2048 -> rb 0..8191 (one per wave)
  size_t row = (size_t)rb * 16 + l15;
  bf16x8 A0 = asb(xb4[row * 8 + g]);
  bf16x8 A1 = asb(xb4[row * 8 + 4 + g]);
  f32x4 acc[16];
  #pragma unroll
  for (int mt = 0; mt < 16; ++mt){
    int r = mt * 16 + l15;
    int byte0 = r * 128 + ((g * 16) ^ ((l15 & 7) << 4));
    int byte1 = r * 128 + ((64 + g * 16) ^ ((l15 & 7) << 4));
    uint4 x0 = *reinterpret_cast<const uint4*>(reinterpret_cast<const char*>(Pl) + byte0);
    uint4 x1 = *reinterpret_cast<const uint4*>(reinterpret_cast<const char*>(Pl) + byte1);
    f32x4 z4 = {0.f, 0.f, 0.f, 0.f};
    z4 = __builtin_amdgcn_mfma_f32_16x16x32_bf16(asb(x0), A0, z4, 0, 0, 0);
    acc[mt] = __builtin_amdgcn_mfma_f32_16x16x32_bf16(asb(x1), A1, acc[mt] = z4, 0, 0, 0);
  }
  if (mode == 0){
    float mx = -3.0e38f;
    #pragma unroll
    for (int mt = 0; mt < 16; ++mt)
      mx = fmaxf(mx, fmaxf(fmaxf(acc[mt][0], acc[mt][1]), fmaxf(acc[mt][2], acc[mt][3])));
    #pragma unroll
    for (int off = 32; off >= 1; off >>= 1)
      mx = fmaxf(mx, __shfl_xor(mx, off, 64));
    if (lane == 0) atomicMax(kmaxp, enc_f32(mx));
  } else {
    float diag = DIAGC * rs[row];
    float msub;
    if (mode == 1){
      float mx = -3.0e38f;
      #pragma unroll
      for (int mt = 0; mt < 16; ++mt)
        mx = fmaxf(mx, fmaxf(fmaxf(acc[mt][0], acc[mt][1]), fmaxf(acc[mt][2], acc[mt][3])));
      mx = fmaxf(mx, __shfl_xor(mx, 16, 64));
      mx = fmaxf(mx, __shfl_xor(mx, 32, 64));
      msub = mx;
    } else {
      msub = gm;
    }
    float bsub = diag + msub;
    #pragma unroll
    for (int mt = 0; mt < 16; ++mt){
      ushort4 pk;
      pk.x = f2bf(RATIO * (expf(acc[mt][0] - bsub) + EPSV));
      pk.y = f2bf(RATIO * (expf(acc[mt][1] - bsub) + EPSV));
      pk.z = f2bf(RATIO * (expf(acc[mt][2] - bsub) + EPSV));
      pk.w = f2bf(RATIO * (expf(acc[mt][3] - bsub) + EPSV));
      *reinterpret_cast<ushort4*>(phi + row * MM + mt * 16 + g * 4) = pk;
    }
  }
}

// ---------------- K3: fused chunk scan ----------------
// Block = (bh, m-quarter of 64). Loops chunks serially, keeping exclusive prefix
// of S[m][d] and z[m] in f32 registers. Emits SpT [BH][NCH][D][M] (exclusive,
// bf16, via LDS transpose) and zc [BH][NCH][M] (exclusive, bf16).
__global__ __launch_bounds__(256) void k_chunkscan(const unsigned short* __restrict__ kp,
                                                   const unsigned short* __restrict__ vTb,
                                                   unsigned short* __restrict__ SpT,
                                                   unsigned short* __restrict__ zc){
  __shared__ unsigned kL[128 * 33];        // kp chunk cols m0r..m0r+63, row stride 33 dw
  __shared__ unsigned short TT[64 * 70];   // transpose tile [mrel][d], stride 70
  int tid = threadIdx.x;
  int w = tid >> 6, lane = tid & 63, l15 = lane & 15, g = lane >> 4;
  int bh = blockIdx.x >> 2, mq = blockIdx.x & 3;
  int m0r = mq * 64;
  const uint4* kpu = reinterpret_cast<const uint4*>(kp);
  const uint4* vTu = reinterpret_cast<const uint4*>(vTb);
  const unsigned short* kL16 = reinterpret_cast<const unsigned short*>(kL);
  float runs[4][4];
  #pragma unroll
  for (int dt = 0; dt < 4; ++dt)
    #pragma unroll
    for (int e = 0; e < 4; ++e) runs[dt][e] = 0.f;
  float runz = 0.f;
  uint4 zero4 = {0u, 0u, 0u, 0u};
  uint4 ones4 = {0x3F803F80u, 0x3F803F80u, 0x3F803F80u, 0x3F803F80u};
  uint4 onesf = (l15 == 0) ? ones4 : zero4;

  for (int c = 0; c < NCH; ++c){
    size_t row0 = (size_t)bh * LL + c * CC;
    for (int idx = tid; idx < 128 * 8; idx += 256){
      int j = idx >> 3, m8 = idx & 7;
      uint4 v = kpu[(row0 + j) * 32 + mq * 8 + m8];
      int base = j * 33 + m8 * 4;
      kL[base + 0] = v.x; kL[base + 1] = v.y; kL[base + 2] = v.z; kL[base + 3] = v.w;
    }
    __syncthreads();

    f32x4 acc[4];
    #pragma unroll
    for (int dt = 0; dt < 4; ++dt) acc[dt] = (f32x4){0.f, 0.f, 0.f, 0.f};
    f32x4 accz = {0.f, 0.f, 0.f, 0.f};
    #pragma unroll
    for (int ks = 0; ks < 4; ++ks){
      PK8 p;
      #pragma unroll
      for (int e = 0; e < 8; ++e)
        p.s[e] = kL16[(ks * 32 + g * 8 + e) * 66 + w * 16 + l15];
      bf16x8 kf = asb(p.u);
      #pragma unroll
      for (int dt = 0; dt < 4; ++dt){
        uint4 vf = vTu[((size_t)(bh * DD) + dt * 16 + l15) * 512 + c * 16 + ks * 4 + g];
        acc[dt] = __builtin_amdgcn_mfma_f32_16x16x32_bf16(asb(vf), kf, acc[dt], 0, 0, 0);
      }
      accz = __builtin_amdgcn_mfma_f32_16x16x32_bf16(asb(onesf), kf, accz, 0, 0, 0);
    }

    // write EXCLUSIVE prefix to TT, then accumulate this chunk
    #pragma unroll
    for (int dt = 0; dt < 4; ++dt){
      unsigned u0 = (unsigned)f2bf(runs[dt][0]) | ((unsigned)f2bf(runs[dt][1]) << 16);
      unsigned u1 = (unsigned)f2bf(runs[dt][2]) | ((unsigned)f2bf(runs[dt][3]) << 16);
      int ui = ((w * 16 + l15) * 70 + dt * 16 + g * 4) >> 1;
      reinterpret_cast<unsigned*>(TT)[ui]     = u0;
      reinterpret_cast<unsigned*>(TT)[ui + 1] = u1;
      runs[dt][0] += acc[dt][0]; runs[dt][1] += acc[dt][1];
      runs[dt][2] += acc[dt][2]; runs[dt][3] += acc[dt][3];
    }
    if (g == 0)
      zc[((size_t)bh * NCH + c) * MM + m0r + w * 16 + l15] = f2bf(runz);
    runz += accz[0];
    __syncthreads();

    // transposed coalesced store: SpT[bh][c][d][m0r..m0r+63]
    {
      int d = tid >> 2, mq2 = tid & 3;
      PK8 lo, hi;
      #pragma unroll
      for (int j = 0; j < 8; ++j){
        lo.s[j] = TT[(mq2 * 16 + j) * 70 + d];
        hi.s[j] = TT[(mq2 * 16 + 8 + j) * 70 + d];
      }
      uint4* dst = reinterpret_cast<uint4*>(
          SpT + (((size_t)bh * NCH + c) * DD + d) * MM + m0r + mq2 * 16);
      dst[0] = lo.u;
      dst[1] = hi.u;
    }
  }
}

// ---------------- K6: MFMA chunk causal attention, CC=128 ----------------
// Block = one (bh, chunk). 4 waves; wave w owns itiles {w, 7-w}.
__global__ __launch_bounds__(256, 4) void k_cattn(const unsigned short* __restrict__ qp,
                                                  const unsigned short* __restrict__ kp,
                                                  const unsigned short* __restrict__ vTb,
                                                  const unsigned short* __restrict__ Spb,
                                                  const unsigned short* __restrict__ zb,
                                                  unsigned short* __restrict__ attnb){
  __shared__ unsigned S4[CC * 64];   // 32 KiB: S[i][j] bf16, byte ^= ((i&7)<<4)
  int tid = threadIdx.x;
  int w = tid >> 6, lane = tid & 63;
  int l15 = lane & 15, g = lane >> 4;
  int blk = blockIdx.x;
  int bh = blk >> 5, c = blk & 31;
  int b = bh >> 3, h = bh & 7;
  size_t row0 = (size_t)blk * CC;
  const uint4* qpu = reinterpret_cast<const uint4*>(qp);
  const uint4* kpu = reinterpret_cast<const uint4*>(kp);
  const uint4* vTu = reinterpret_cast<const uint4*>(vTb);
  const uint4* Spu = reinterpret_cast<const uint4*>(Spb);
  const uint4* zbu = reinterpret_cast<const uint4*>(zb);

  int its[2] = { w, 7 - w };
  uint4 qf[2][8];
  #pragma unroll
  for (int t = 0; t < 2; ++t){
    size_t qrow = row0 + its[t] * 16 + l15;
    #pragma unroll
    for (int ks = 0; ks < 8; ++ks)
      qf[t][ks] = qpu[qrow * 32 + ks * 4 + g];
  }

  // ---- phase 1: scores ----
  #pragma unroll
  for (int t = 0; t < 2; ++t){
    int it = its[t];
    int i = it * 16 + l15;
    int jtmax = it | 1;
    for (int jt = 0; jt <= jtmax; ++jt){
      f32x4 acc = {0.f, 0.f, 0.f, 0.f};
      size_t krow = row0 + jt * 16 + l15;
      #pragma unroll
      for (int ks = 0; ks < 8; ++ks){
        uint4 kfu = kpu[krow * 32 + ks * 4 + g];
        acc = __builtin_amdgcn_mfma_f32_16x16x32_bf16(asb(kfu), asb(qf[t][ks]), acc, 0, 0, 0);
      }
      int jb = jt * 16 + g * 4;
      PK2 pk;
      pk.s.x = (jb + 0 <= i) ? f2bf(acc[0]) : (unsigned short)0;
      pk.s.y = (jb + 1 <= i) ? f2bf(acc[1]) : (unsigned short)0;
      pk.s.z = (jb + 2 <= i) ? f2bf(acc[2]) : (unsigned short)0;
      pk.s.w = (jb + 3 <= i) ? f2bf(acc[3]) : (unsigned short)0;
      int byte = i * 256 + ((jb * 2) ^ ((i & 7) << 4));
      *reinterpret_cast<uint2*>(&S4[byte >> 2]) = pk.u;
    }
  }
  // no barrier: each wave reads only S rows it wrote.

  // ---- phase 2: PV + prefix ----
  uint4 zero4 = {0u, 0u, 0u, 0u};
  uint4 ones4 = {0x3F803F80u, 0x3F803F80u, 0x3F803F80u, 0x3F803F80u};
  #pragma unroll
  for (int t = 0; t < 2; ++t){
    int it = its[t];
    int i = it * 16 + l15;
    f32x4 acc[5];
    #pragma unroll
    for (int a5 = 0; a5 < 5; ++a5) acc[a5] = (f32x4){0.f, 0.f, 0.f, 0.f};
    int ksv = (it >> 1) + 1;
    for (int ks = 0; ks < ksv; ++ks){
      int byte = i * 256 + ((ks * 64 + g * 16) ^ ((i & 7) << 4));
      uint4 sfu = *reinterpret_cast<const uint4*>(&S4[byte >> 2]);
      bf16x8 sf = asb(sfu);
      #pragma unroll
      for (int dt = 0; dt < 4; ++dt){
        size_t vrow = (size_t)(bh * DD + dt * 16 + l15);
        uint4 vfu = vTu[vrow * 512 + c * 16 + ks * 4 + g];
        acc[dt] = __builtin_amdgcn_mfma_f32_16x16x32_bf16(asb(vfu), sf, acc[dt], 0, 0, 0);
      }
      uint4 of = (l15 == 0) ? ones4 : zero4;
      acc[4] = __builtin_amdgcn_mfma_f32_16x16x32_bf16(asb(of), sf, acc[4], 0, 0, 0);
    }
    #pragma unroll
    for (int ks = 0; ks < 8; ++ks){
      bf16x8 qb = asb(qf[t][ks]);
      #pragma unroll
      for (int dt = 0; dt < 4; ++dt){
        size_t prow = (size_t)blk * DD + dt * 16 + l15;
        acc[dt] = __builtin_amdgcn_mfma_f32_16x16x32_bf16(asb(Spu[prow * 32 + ks * 4 + g]), qb, acc[dt], 0, 0, 0);
      }
      uint4 zf = (l15 == 0) ? zbu[blk * 32 + ks * 4 + g] : zero4;
      acc[4] = __builtin_amdgcn_mfma_f32_16x16x32_bf16(asb(zf), qb, acc[4], 0, 0, 0);
    }
    float den = __shfl(acc[4][0], l15, 64);
    float inv = 1.f / den;
    size_t obase = ((size_t)(b * LL + c * CC + i)) * EE + h * DD;
    #pragma unroll
    for (int dt = 0; dt < 4; ++dt){
      ushort4 pk;
      pk.x = f2bf(acc[dt][0] * inv); pk.y = f2bf(acc[dt][1] * inv);
      pk.z = f2bf(acc[dt][2] * inv); pk.w = f2bf(acc[dt][3] * inv);
      *reinterpret_cast<ushort4*>(attnb + obase + dt * 16 + g * 4) = pk;
    }
  }
}

// ---------------- K7a: Wout f32 -> bf16 ----------------
__global__ __launch_bounds__(256) void k_cvtW(const float* __restrict__ W,
                                              unsigned short* __restrict__ Wb){
  int idx = blockIdx.x * 256 + threadIdx.x;
  float2 v = reinterpret_cast<const float2*>(W)[idx];
  unsigned u = ((unsigned)f2bf(v.y) << 16) | (unsigned)f2bf(v.x);
  reinterpret_cast<unsigned*>(Wb)[idx] = u;
}

// ---------------- K7: MFMA out-proj: out = attnb @ Woutb^T + bout ----------------
__global__ __launch_bounds__(256) void k_proj_M(const unsigned short* __restrict__ attnb,
                                                const unsigned short* __restrict__ Woutb,
                                                const float* __restrict__ bout,
                                                float* __restrict__ out){
  int tid = threadIdx.x;
  int w = tid >> 6, lane = tid & 63, l15 = lane & 15, g = lane >> 4;
  int rb = blockIdx.x >> 3, eb = blockIdx.x & 7;
  int r0 = rb * 64, e0 = eb * 64;
  int r = r0 + w * 16 + l15;
  const uint4* at4 = reinterpret_cast<const uint4*>(attnb);
  const uint4* Wo4 = reinterpret_cast<const uint4*>(Woutb);
  f32x4 acc[4];
  #pragma unroll
  for (int ct = 0; ct < 4; ++ct) acc[ct] = (f32x4){0.f, 0.f, 0.f, 0.f};
  for (int ks = 0; ks < 16; ++ks){
    uint4 bfrag = at4[((size_t)r * EE + ks * 32 + g * 8) >> 3];
    #pragma unroll
    for (int ct = 0; ct < 4; ++ct){
      uint4 af = Wo4[((size_t)(e0 + ct * 16 + l15) * EE + ks * 32 + g * 8) >> 3];
      acc[ct] = __builtin_amdgcn_mfma_f32_16x16x32_bf16(asb(af), asb(bfrag), acc[ct], 0, 0, 0);
    }
  }
  #pragma unroll
  for (int ct = 0; ct < 4; ++ct){
    int e = e0 + ct * 16 + g * 4;
    float4 bo = *reinterpret_cast<const float4*>(bout + e);
    float4 o;
    o.x = acc[ct][0] + bo.x; o.y = acc[ct][1] + bo.y;
    o.z = acc[ct][2] + bo.z; o.w = acc[ct][3] + bo.w;
    *reinterpret_cast<float4*>(out + (size_t)r * EE + e) = o;
  }
}

extern "C" void kernel_launch(void* const* d_in, const int* in_sizes, int n_in,
                              void* d_out, int out_size, void* d_ws, size_t ws_size,
                              hipStream_t stream){
  const float* queries = (const float*)d_in[0];
  const float* keys    = (const float*)d_in[1];
  const float* values  = (const float*)d_in[2];
  const float* Wq      = (const float*)d_in[3];
  const float* Wk      = (const float*)d_in[4];
  const float* Wv      = (const float*)d_in[5];
  const float* Wout    = (const float*)d_in[6];
  const float* bout    = (const float*)d_in[7];
  const float* proj    = (const float*)d_in[8];

  // workspace layout (max 220.2 MB; 236.2 MB proven available in round 2)
  char* ws = (char*)d_ws;
  unsigned short* qhb  = (unsigned short*)(ws + 0);           // 16.8M [BH,L,D] bf16
  unsigned short* khb  = (unsigned short*)(ws + 16777216);    // 16.8M
  unsigned short* vTb  = (unsigned short*)(ws + 33554432);    // 16.8M [BH,D,L] bf16
  unsigned short* qp   = (unsigned short*)(ws + 50331648);    // 67M   [BH,L,M] bf16
  unsigned short* kp   = (unsigned short*)(ws + 117440512);   // 67M
  unsigned short* SpT  = (unsigned short*)(ws + 184549376);   // 33.5M [BH,NCH,D,M] bf16 (exclusive)
  unsigned short* zc   = (unsigned short*)(ws + 218103808);   // 0.5M  [BH,NCH,M] bf16 (exclusive)
  float*          rsq  = (float*)(ws + 218628096);            // 0.5M  [BH*L]
  float*          rsk  = (float*)(ws + 219152384);            // 0.5M
  unsigned short* Woutb= (unsigned short*)(ws + 219676672);   // 0.5M  [E,E] bf16
  unsigned*       kmax = (unsigned*)(ws + 220200960);         // 4
  unsigned short* attnb= qhb;   // qhb dead after k_phiM(q); attnb written by k_cattn
  float*          out  = (float*)d_out;

  hipMemsetAsync(kmax, 0, 4, stream);

  k_transform_b<<<dim3(BHN * LL / 4), dim3(256), 0, stream>>>(queries, Wq, qhb, rsq);
  k_transform_b<<<dim3(BHN * LL / 4), dim3(256), 0, stream>>>(keys,    Wk, khb, rsk);
  k_transform_vT<<<dim3(BHN * (LL / 64)), dim3(256), 0, stream>>>(values, Wv, vTb);
  k_cvtW<<<dim3(512), dim3(256), 0, stream>>>(Wout, Woutb);

  k_phiM<<<dim3(2048), dim3(256), 0, stream>>>(khb, rsk, proj, kmax, nullptr, 0);
  k_phiM<<<dim3(2048), dim3(256), 0, stream>>>(qhb, rsq, proj, kmax, qp, 1);
  k_phiM<<<dim3(2048), dim3(256), 0, stream>>>(khb, rsk, proj, kmax, kp, 2);

  k_chunkscan<<<dim3(BHN * 4), dim3(256), 0, stream>>>(kp, vTb, SpT, zc);

  k_cattn<<<dim3(BHN * NCH), dim3(256), 0, stream>>>(qp, kp, vTb, SpT, zc, attnb);

  k_proj_M<<<dim3((BB * LL / 64) * (EE / 64)), dim3(256), 0, stream>>>(attnb, Woutb, bout, out);
}

// Round 5
// 682.334 us; speedup vs baseline: 1.2007x; 1.2007x over previous
//
#include <hip/hip_runtime.h>
#include <hip/hip_bf16.h>

// Performer (FAVOR+) causal linear self-attention, MI355X round 4.
// B=4 L=4096 E=512 H=8 D=64 M=256 chunk=128.
// Round 4: replace the latency-starved 128-block chunkscan with a 1024-block
// per-chunk MFMA kernel + vectorized in-place exclusive prefix.

#define BB 4
#define LL 4096
#define EE 512
#define HH 8
#define DD 64
#define MM 256
#define CC 128
#define NCH 32   // L / CC
#define BHN 32   // B * H

constexpr float DN    = 0.35355339059327373f; // 64^-0.25
constexpr float DIAGC = 0.0625f;              // 0.5 * dn^2
constexpr float RATIO = 0.0625f;              // 256^-0.5
constexpr float EPSV  = 1e-4f;

typedef __attribute__((ext_vector_type(8))) short bf16x8;
typedef __attribute__((ext_vector_type(4))) float f32x4;
union FU { uint4 u; bf16x8 b; };
__device__ __forceinline__ bf16x8 asb(uint4 u){ FU f; f.u = u; return f.b; }
union PK2 { ushort4 s; uint2 u; };
union PK8 { unsigned short s[8]; uint4 u; };

__device__ __forceinline__ unsigned short f2bf(float f){
  unsigned u = __float_as_uint(f);
  u = u + 0x7FFFu + ((u >> 16) & 1u);   // RTNE
  return (unsigned short)(u >> 16);
}
__device__ __forceinline__ float bfl(unsigned u){ return __uint_as_float(u << 16); }
__device__ __forceinline__ unsigned enc_f32(float f){
  unsigned u = __float_as_uint(f);
  return (u & 0x80000000u) ? ~u : (u | 0x80000000u);
}
__device__ __forceinline__ float dec_f32(unsigned u){
  unsigned v = (u & 0x80000000u) ? (u & 0x7FFFFFFFu) : ~u;
  return __uint_as_float(v);
}
__device__ __forceinline__ uint4 pack8(float4 a, float4 b){
  PK8 p;
  p.s[0] = f2bf(a.x); p.s[1] = f2bf(a.y); p.s[2] = f2bf(a.z); p.s[3] = f2bf(a.w);
  p.s[4] = f2bf(b.x); p.s[5] = f2bf(b.y); p.s[6] = f2bf(b.z); p.s[7] = f2bf(b.w);
  return p.u;
}

// ---------------- K1: head-split + DxD projection -> bf16 out + rowsum(out^2) ----------------
__global__ __launch_bounds__(256) void k_transform_b(const float* __restrict__ x,
                                                     const float* __restrict__ W,
                                                     unsigned short* __restrict__ xb,
                                                     float* __restrict__ rs){
  __shared__ float Wt[DD * 65];   // Wt[dp*65+d] = W[d][dp]
  __shared__ float xr[4][DD];
  int tid = threadIdx.x;
  for (int i = tid; i < DD * DD; i += 256){
    int d = i >> 6, dp = i & 63;
    Wt[dp * 65 + d] = W[i];
  }
  int bh = blockIdx.x >> 10;
  int l0 = (blockIdx.x & 1023) << 2;
  int b = bh >> 3, h = bh & 7;
  int r = tid >> 6, d = tid & 63;
  xr[r][d] = x[((size_t)(b * LL + l0 + r)) * EE + h * DD + d];
  __syncthreads();
  float acc = 0.f;
  #pragma unroll
  for (int dp = 0; dp < DD; ++dp)
    acc += xr[r][dp] * Wt[dp * 65 + d];
  size_t row = (size_t)bh * LL + l0 + r;
  float sq = acc * acc;
  #pragma unroll
  for (int off = 32; off >= 1; off >>= 1)
    sq += __shfl_xor(sq, off, 64);
  if (d == 0) rs[row] = sq;
  float other = __shfl_xor(acc, 1, 64);
  if ((d & 1) == 0){
    unsigned u = (unsigned)f2bf(acc) | ((unsigned)f2bf(other) << 16);
    reinterpret_cast<unsigned*>(xb)[row * 32 + (d >> 1)] = u;
  }
}

// ---------------- K1v: v transform -> transposed bf16 vT [BH][D][L] ----------------
__global__ __launch_bounds__(256) void k_transform_vT(const float* __restrict__ x,
                                                      const float* __restrict__ W,
                                                      unsigned short* __restrict__ vTb){
  __shared__ float Wt[DD * 65];
  __shared__ float T[64 * 65];
  int tid = threadIdx.x;
  for (int i = tid; i < DD * DD; i += 256){
    int d = i >> 6, dp = i & 63;
    Wt[dp * 65 + d] = W[i];
  }
  __syncthreads();
  int bh = blockIdx.x >> 6;               // grid = BH * (L/64)
  int l0 = (blockIdx.x & 63) << 6;
  int b = bh >> 3, h = bh & 7;
  int r = tid >> 6, lane = tid & 63;
  for (int g = 0; g < 16; ++g){
    int l = g * 4 + r;
    float xv = x[((size_t)(b * LL + l0 + l)) * EE + h * DD + lane];
    float acc = 0.f;
    #pragma unroll
    for (int dp = 0; dp < DD; ++dp)
      acc += __shfl(xv, dp, 64) * Wt[dp * 65 + lane];
    T[l * 65 + lane] = acc;
  }
  __syncthreads();
  int dd = tid >> 2, e0 = (tid & 3) << 4;
  PK8 p0, p1;
  #pragma unroll
  for (int jj = 0; jj < 8; ++jj){
    p0.s[jj] = f2bf(T[(e0 + jj) * 65 + dd]);
    p1.s[jj] = f2bf(T[(e0 + 8 + jj) * 65 + dd]);
  }
  uint4* op = reinterpret_cast<uint4*>(vTb + ((size_t)(bh * DD + dd)) * LL + l0 + e0);
  op[0] = p0.u;
  op[1] = p1.u;
}

// ---------------- K2: MFMA phi / kmax (bf16 inputs + precomputed rowsum) ----------------
// mode 0: global max of xd(k) -> atomicMax. mode 1: query phi. mode 2: key phi.
__global__ __launch_bounds__(256) void k_phiM(const unsigned short* __restrict__ xb,
                                              const float* __restrict__ rs,
                                              const float* __restrict__ proj,
                                              unsigned* __restrict__ kmaxp,
                                              unsigned short* __restrict__ phi,
                                              int mode){
  __shared__ unsigned short Pl[256 * 64];   // swizzled bf16 dn*proj, 32 KiB
  int tid = threadIdx.x;
  const float4* proj4 = reinterpret_cast<const float4*>(proj);
  for (int idx = tid; idx < 2048; idx += 256){
    int m = idx >> 3, c = idx & 7;
    float4 a = proj4[m * 16 + c * 2];
    float4 b = proj4[m * 16 + c * 2 + 1];
    a.x *= DN; a.y *= DN; a.z *= DN; a.w *= DN;
    b.x *= DN; b.y *= DN; b.z *= DN; b.w *= DN;
    int byte = m * 128 + ((c * 16) ^ ((m & 7) << 4));
    *reinterpret_cast<uint4*>(reinterpret_cast<char*>(Pl) + byte) = pack8(a, b);
  }
  __syncthreads();
  int w = tid >> 6, lane = tid & 63, l15 = lane & 15, g = lane >> 4;
  const uint4* xb4 = reinterpret_cast<const uint4*>(xb);
  float gm = (mode == 2) ? dec_f32(*kmaxp) : 0.f;
  int rb = blockIdx.x * 4 + w;              // grid 2048 -> rb 0..8191 (one per wave)
  size_t row = (size_t)rb * 16 + l15;
  bf16x8 A0 = asb(xb4[row * 8 + g]);
  bf16x8 A1 = asb(xb4[row * 8 + 4 + g]);
  f32x4 acc[16];
  #pragma unroll
  for (int mt = 0; mt < 16; ++mt){
    int r = mt * 16 + l15;
    int byte0 = r * 128 + ((g * 16) ^ ((l15 & 7) << 4));
    int byte1 = r * 128 + ((64 + g * 16) ^ ((l15 & 7) << 4));
    uint4 x0 = *reinterpret_cast<const uint4*>(reinterpret_cast<const char*>(Pl) + byte0);
    uint4 x1 = *reinterpret_cast<const uint4*>(reinterpret_cast<const char*>(Pl) + byte1);
    f32x4 z4 = {0.f, 0.f, 0.f, 0.f};
    z4 = __builtin_amdgcn_mfma_f32_16x16x32_bf16(asb(x0), A0, z4, 0, 0, 0);
    acc[mt] = __builtin_amdgcn_mfma_f32_16x16x32_bf16(asb(x1), A1, z4, 0, 0, 0);
  }
  if (mode == 0){
    float mx = -3.0e38f;
    #pragma unroll
    for (int mt = 0; mt < 16; ++mt)
      mx = fmaxf(mx, fmaxf(fmaxf(acc[mt][0], acc[mt][1]), fmaxf(acc[mt][2], acc[mt][3])));
    #pragma unroll
    for (int off = 32; off >= 1; off >>= 1)
      mx = fmaxf(mx, __shfl_xor(mx, off, 64));
    if (lane == 0) atomicMax(kmaxp, enc_f32(mx));
  } else {
    float diag = DIAGC * rs[row];
    float msub;
    if (mode == 1){
      float mx = -3.0e38f;
      #pragma unroll
      for (int mt = 0; mt < 16; ++mt)
        mx = fmaxf(mx, fmaxf(fmaxf(acc[mt][0], acc[mt][1]), fmaxf(acc[mt][2], acc[mt][3])));
      mx = fmaxf(mx, __shfl_xor(mx, 16, 64));
      mx = fmaxf(mx, __shfl_xor(mx, 32, 64));
      msub = mx;
    } else {
      msub = gm;
    }
    float bsub = diag + msub;
    #pragma unroll
    for (int mt = 0; mt < 16; ++mt){
      ushort4 pk;
      pk.x = f2bf(RATIO * (expf(acc[mt][0] - bsub) + EPSV));
      pk.y = f2bf(RATIO * (expf(acc[mt][1] - bsub) + EPSV));
      pk.z = f2bf(RATIO * (expf(acc[mt][2] - bsub) + EPSV));
      pk.w = f2bf(RATIO * (expf(acc[mt][3] - bsub) + EPSV));
      *reinterpret_cast<ushort4*>(phi + row * MM + mt * 16 + g * 4) = pk;
    }
  }
}

// ---------------- K3: per-chunk MFMA KV sums ----------------
// Block = (bh, chunk). 4 waves; wave w owns m-quarter w*64..w*64+63 with a
// private stride-33-dword LDS panel holding kp[chunk][m-quarter] (conflict-free
// staging and transposed u16 reads). Emits per-chunk S_c[d][m] bf16 + z_c f32.
__global__ __launch_bounds__(256, 2) void k_chunkKV3(const unsigned short* __restrict__ kp,
                                                     const unsigned short* __restrict__ vTb,
                                                     unsigned short* __restrict__ SpT,
                                                     float* __restrict__ zf){
  __shared__ unsigned kL[4 * 128 * 33];    // 67.6 KiB, per-wave panels
  int tid = threadIdx.x;
  int w = tid >> 6, lane = tid & 63, l15 = lane & 15, g = lane >> 4;
  int blk = blockIdx.x;
  int bh = blk >> 5, c = blk & 31;
  size_t row0 = (size_t)bh * LL + c * CC;
  const uint4* kpu = reinterpret_cast<const uint4*>(kp);
  const uint4* vTu = reinterpret_cast<const uint4*>(vTb);
  unsigned* kLw = kL + w * 128 * 33;
  const unsigned short* kL16w = reinterpret_cast<const unsigned short*>(kLw);

  // stage: wave w loads kp[chunk rows][m = w*64 .. w*64+63]
  for (int idx = lane; idx < 128 * 8; idx += 64){
    int j = idx >> 3, m8 = idx & 7;
    uint4 v = kpu[(row0 + j) * 32 + w * 8 + m8];
    int base = j * 33 + m8 * 4;
    kLw[base + 0] = v.x; kLw[base + 1] = v.y; kLw[base + 2] = v.z; kLw[base + 3] = v.w;
  }
  __syncthreads();

  // cache vT frags: vf[dt][ks], rows d = dt*16+l15, k = ks*32+g*8..
  uint4 vf[4][4];
  #pragma unroll
  for (int dt = 0; dt < 4; ++dt)
    #pragma unroll
    for (int ks = 0; ks < 4; ++ks)
      vf[dt][ks] = vTu[((size_t)(bh * DD + dt * 16 + l15)) * 512 + c * 16 + ks * 4 + g];

  uint4 zero4 = {0u, 0u, 0u, 0u};
  uint4 ones4 = {0x3F803F80u, 0x3F803F80u, 0x3F803F80u, 0x3F803F80u};
  uint4 onesf = (l15 == 0) ? ones4 : zero4;

  #pragma unroll
  for (int mtr = 0; mtr < 4; ++mtr){
    f32x4 acc[4];
    #pragma unroll
    for (int dt = 0; dt < 4; ++dt) acc[dt] = (f32x4){0.f, 0.f, 0.f, 0.f};
    f32x4 accz = {0.f, 0.f, 0.f, 0.f};
    #pragma unroll
    for (int ks = 0; ks < 4; ++ks){
      PK8 p;
      #pragma unroll
      for (int e = 0; e < 8; ++e)
        p.s[e] = kL16w[(ks * 32 + g * 8 + e) * 66 + mtr * 16 + l15];
      bf16x8 kfb = asb(p.u);   // A-frag rows m = w*64 + mtr*16 + l15
      #pragma unroll
      for (int dt = 0; dt < 4; ++dt)
        acc[dt] = __builtin_amdgcn_mfma_f32_16x16x32_bf16(kfb, asb(vf[dt][ks]), acc[dt], 0, 0, 0);
      accz = __builtin_amdgcn_mfma_f32_16x16x32_bf16(kfb, asb(onesf), accz, 0, 0, 0);
    }
    int m0 = w * 64 + mtr * 16;
    #pragma unroll
    for (int dt = 0; dt < 4; ++dt){
      ushort4 pk;
      pk.x = f2bf(acc[dt][0]); pk.y = f2bf(acc[dt][1]);
      pk.z = f2bf(acc[dt][2]); pk.w = f2bf(acc[dt][3]);
      *reinterpret_cast<ushort4*>(SpT + ((size_t)blk * DD + dt * 16 + l15) * MM + m0 + g * 4) = pk;
    }
    if (l15 == 0){
      float4 o; o.x = accz[0]; o.y = accz[1]; o.z = accz[2]; o.w = accz[3];
      *reinterpret_cast<float4*>(zf + (size_t)blk * MM + m0 + g * 4) = o;
    }
  }
}

// ---------------- K5a: in-place exclusive prefix over chunk planes (bf16, x8 vec) ----------
__global__ __launch_bounds__(256) void k_prefix_ip(unsigned short* __restrict__ buf){
  const int per8 = (DD * MM) / 8;          // 2048 uint4-groups per plane
  int idx = blockIdx.x * 256 + threadIdx.x;  // grid 2048 -> BHN * per8 threads
  int bh = idx / per8, r8 = idx - bh * per8;
  float run[8];
  #pragma unroll
  for (int e = 0; e < 8; ++e) run[e] = 0.f;
  for (int c = 0; c < NCH; ++c){
    size_t a = (((size_t)bh * NCH + c) * (DD * MM)) >> 3;
    uint4* p = reinterpret_cast<uint4*>(buf) + a + r8;
    uint4 v = *p;
    PK8 t; t.u = v;
    PK8 o;
    #pragma unroll
    for (int e = 0; e < 8; ++e){
      o.s[e] = f2bf(run[e]);
      run[e] += bfl((unsigned)t.s[e]);
    }
    *p = o.u;
  }
}

// ---------------- K5b: z prefix f32 -> exclusive bf16 ----------------
__global__ __launch_bounds__(256) void k_prefix_z(const float* __restrict__ zf,
                                                  unsigned short* __restrict__ zb){
  const int per8 = MM / 8;                 // 32 groups per plane
  int idx = blockIdx.x * 256 + threadIdx.x;  // grid 4 -> BHN * 32 threads
  int bh = idx / per8, r8 = idx - bh * per8;
  float run[8];
  #pragma unroll
  for (int e = 0; e < 8; ++e) run[e] = 0.f;
  for (int c = 0; c < NCH; ++c){
    size_t base = ((size_t)bh * NCH + c) * MM + r8 * 8;
    float4 v0 = *reinterpret_cast<const float4*>(zf + base);
    float4 v1 = *reinterpret_cast<const float4*>(zf + base + 4);
    PK8 o;
    #pragma unroll
    for (int e = 0; e < 8; ++e) o.s[e] = f2bf(run[e]);
    run[0] += v0.x; run[1] += v0.y; run[2] += v0.z; run[3] += v0.w;
    run[4] += v1.x; run[5] += v1.y; run[6] += v1.z; run[7] += v1.w;
    *reinterpret_cast<uint4*>(zb + base) = o.u;
  }
}

// ---------------- K6: MFMA chunk causal attention, CC=128 ----------------
// Block = one (bh, chunk). 4 waves; wave w owns itiles {w, 7-w}.
__global__ __launch_bounds__(256, 4) void k_cattn(const unsigned short* __restrict__ qp,
                                                  const unsigned short* __restrict__ kp,
                                                  const unsigned short* __restrict__ vTb,
                                                  const unsigned short* __restrict__ Spb,
                                                  const unsigned short* __restrict__ zb,
                                                  unsigned short* __restrict__ attnb){
  __shared__ unsigned S4[CC * 64];   // 32 KiB: S[i][j] bf16, byte ^= ((i&7)<<4)
  int tid = threadIdx.x;
  int w = tid >> 6, lane = tid & 63;
  int l15 = lane & 15, g = lane >> 4;
  int blk = blockIdx.x;
  int bh = blk >> 5, c = blk & 31;
  int b = bh >> 3, h = bh & 7;
  size_t row0 = (size_t)blk * CC;
  const uint4* qpu = reinterpret_cast<const uint4*>(qp);
  const uint4* kpu = reinterpret_cast<const uint4*>(kp);
  const uint4* vTu = reinterpret_cast<const uint4*>(vTb);
  const uint4* Spu = reinterpret_cast<const uint4*>(Spb);
  const uint4* zbu = reinterpret_cast<const uint4*>(zb);

  int its[2] = { w, 7 - w };
  uint4 qf[2][8];
  #pragma unroll
  for (int t = 0; t < 2; ++t){
    size_t qrow = row0 + its[t] * 16 + l15;
    #pragma unroll
    for (int ks = 0; ks < 8; ++ks)
      qf[t][ks] = qpu[qrow * 32 + ks * 4 + g];
  }

  // ---- phase 1: scores ----
  #pragma unroll
  for (int t = 0; t < 2; ++t){
    int it = its[t];
    int i = it * 16 + l15;
    int jtmax = it | 1;
    for (int jt = 0; jt <= jtmax; ++jt){
      f32x4 acc = {0.f, 0.f, 0.f, 0.f};
      size_t krow = row0 + jt * 16 + l15;
      #pragma unroll
      for (int ks = 0; ks < 8; ++ks){
        uint4 kfu = kpu[krow * 32 + ks * 4 + g];
        acc = __builtin_amdgcn_mfma_f32_16x16x32_bf16(asb(kfu), asb(qf[t][ks]), acc, 0, 0, 0);
      }
      int jb = jt * 16 + g * 4;
      PK2 pk;
      pk.s.x = (jb + 0 <= i) ? f2bf(acc[0]) : (unsigned short)0;
      pk.s.y = (jb + 1 <= i) ? f2bf(acc[1]) : (unsigned short)0;
      pk.s.z = (jb + 2 <= i) ? f2bf(acc[2]) : (unsigned short)0;
      pk.s.w = (jb + 3 <= i) ? f2bf(acc[3]) : (unsigned short)0;
      int byte = i * 256 + ((jb * 2) ^ ((i & 7) << 4));
      *reinterpret_cast<uint2*>(&S4[byte >> 2]) = pk.u;
    }
  }
  // no barrier: each wave reads only S rows it wrote.

  // ---- phase 2: PV + prefix ----
  uint4 zero4 = {0u, 0u, 0u, 0u};
  uint4 ones4 = {0x3F803F80u, 0x3F803F80u, 0x3F803F80u, 0x3F803F80u};
  #pragma unroll
  for (int t = 0; t < 2; ++t){
    int it = its[t];
    int i = it * 16 + l15;
    f32x4 acc[5];
    #pragma unroll
    for (int a5 = 0; a5 < 5; ++a5) acc[a5] = (f32x4){0.f, 0.f, 0.f, 0.f};
    int ksv = (it >> 1) + 1;
    for (int ks = 0; ks < ksv; ++ks){
      int byte = i * 256 + ((ks * 64 + g * 16) ^ ((i & 7) << 4));
      uint4 sfu = *reinterpret_cast<const uint4*>(&S4[byte >> 2]);
      bf16x8 sf = asb(sfu);
      #pragma unroll
      for (int dt = 0; dt < 4; ++dt){
        size_t vrow = (size_t)(bh * DD + dt * 16 + l15);
        uint4 vfu = vTu[vrow * 512 + c * 16 + ks * 4 + g];
        acc[dt] = __builtin_amdgcn_mfma_f32_16x16x32_bf16(asb(vfu), sf, acc[dt], 0, 0, 0);
      }
      uint4 of = (l15 == 0) ? ones4 : zero4;
      acc[4] = __builtin_amdgcn_mfma_f32_16x16x32_bf16(asb(of), sf, acc[4], 0, 0, 0);
    }
    #pragma unroll
    for (int ks = 0; ks < 8; ++ks){
      bf16x8 qb = asb(qf[t][ks]);
      #pragma unroll
      for (int dt = 0; dt < 4; ++dt){
        size_t prow = (size_t)blk * DD + dt * 16 + l15;
        acc[dt] = __builtin_amdgcn_mfma_f32_16x16x32_bf16(asb(Spu[prow * 32 + ks * 4 + g]), qb, acc[dt], 0, 0, 0);
      }
      uint4 zfr = (l15 == 0) ? zbu[blk * 32 + ks * 4 + g] : zero4;
      acc[4] = __builtin_amdgcn_mfma_f32_16x16x32_bf16(asb(zfr), qb, acc[4], 0, 0, 0);
    }
    float den = __shfl(acc[4][0], l15, 64);
    float inv = 1.f / den;
    size_t obase = ((size_t)(b * LL + c * CC + i)) * EE + h * DD;
    #pragma unroll
    for (int dt = 0; dt < 4; ++dt){
      ushort4 pk;
      pk.x = f2bf(acc[dt][0] * inv); pk.y = f2bf(acc[dt][1] * inv);
      pk.z = f2bf(acc[dt][2] * inv); pk.w = f2bf(acc[dt][3] * inv);
      *reinterpret_cast<ushort4*>(attnb + obase + dt * 16 + g * 4) = pk;
    }
  }
}

// ---------------- K7a: Wout f32 -> bf16 ----------------
__global__ __launch_bounds__(256) void k_cvtW(const float* __restrict__ W,
                                              unsigned short* __restrict__ Wb){
  int idx = blockIdx.x * 256 + threadIdx.x;
  float2 v = reinterpret_cast<const float2*>(W)[idx];
  unsigned u = ((unsigned)f2bf(v.y) << 16) | (unsigned)f2bf(v.x);
  reinterpret_cast<unsigned*>(Wb)[idx] = u;
}

// ---------------- K7: MFMA out-proj: out = attnb @ Woutb^T + bout ----------------
__global__ __launch_bounds__(256) void k_proj_M(const unsigned short* __restrict__ attnb,
                                                const unsigned short* __restrict__ Woutb,
                                                const float* __restrict__ bout,
                                                float* __restrict__ out){
  int tid = threadIdx.x;
  int w = tid >> 6, lane = tid & 63, l15 = lane & 15, g = lane >> 4;
  int rb = blockIdx.x >> 3, eb = blockIdx.x & 7;
  int r0 = rb * 64, e0 = eb * 64;
  int r = r0 + w * 16 + l15;
  const uint4* at4 = reinterpret_cast<const uint4*>(attnb);
  const uint4* Wo4 = reinterpret_cast<const uint4*>(Woutb);
  f32x4 acc[4];
  #pragma unroll
  for (int ct = 0; ct < 4; ++ct) acc[ct] = (f32x4){0.f, 0.f, 0.f, 0.f};
  for (int ks = 0; ks < 16; ++ks){
    uint4 bfrag = at4[((size_t)r * EE + ks * 32 + g * 8) >> 3];
    #pragma unroll
    for (int ct = 0; ct < 4; ++ct){
      uint4 af = Wo4[((size_t)(e0 + ct * 16 + l15) * EE + ks * 32 + g * 8) >> 3];
      acc[ct] = __builtin_amdgcn_mfma_f32_16x16x32_bf16(asb(af), asb(bfrag), acc[ct], 0, 0, 0);
    }
  }
  #pragma unroll
  for (int ct = 0; ct < 4; ++ct){
    int e = e0 + ct * 16 + g * 4;
    float4 bo = *reinterpret_cast<const float4*>(bout + e);
    float4 o;
    o.x = acc[ct][0] + bo.x; o.y = acc[ct][1] + bo.y;
    o.z = acc[ct][2] + bo.z; o.w = acc[ct][3] + bo.w;
    *reinterpret_cast<float4*>(out + (size_t)r * EE + e) = o;
  }
}

extern "C" void kernel_launch(void* const* d_in, const int* in_sizes, int n_in,
                              void* d_out, int out_size, void* d_ws, size_t ws_size,
                              hipStream_t stream){
  const float* queries = (const float*)d_in[0];
  const float* keys    = (const float*)d_in[1];
  const float* values  = (const float*)d_in[2];
  const float* Wq      = (const float*)d_in[3];
  const float* Wk      = (const float*)d_in[4];
  const float* Wv      = (const float*)d_in[5];
  const float* Wout    = (const float*)d_in[6];
  const float* bout    = (const float*)d_in[7];
  const float* proj    = (const float*)d_in[8];

  // workspace layout (221.3 MB; 225 MB proven in round 0)
  char* ws = (char*)d_ws;
  unsigned short* qhb  = (unsigned short*)(ws + 0);           // 16.8M [BH,L,D] bf16
  unsigned short* khb  = (unsigned short*)(ws + 16777216);    // 16.8M
  unsigned short* vTb  = (unsigned short*)(ws + 33554432);    // 16.8M [BH,D,L] bf16
  unsigned short* qp   = (unsigned short*)(ws + 50331648);    // 67M   [BH,L,M] bf16
  unsigned short* kp   = (unsigned short*)(ws + 117440512);   // 67M
  unsigned short* SpT  = (unsigned short*)(ws + 184549376);   // 33.5M [BH,NCH,D,M] bf16 (sums -> exclusive in-place)
  float*          zfbuf= (float*)(ws + 218103808);            // 1.0M  [BH,NCH,M] f32 (per-chunk sums)
  unsigned short* zb   = (unsigned short*)(ws + 219152384);   // 0.5M  [BH,NCH,M] bf16 (exclusive)
  float*          rsq  = (float*)(ws + 219676672);            // 0.5M  [BH*L]
  float*          rsk  = (float*)(ws + 220200960);            // 0.5M
  unsigned short* Woutb= (unsigned short*)(ws + 220725248);   // 0.5M  [E,E] bf16
  unsigned*       kmax = (unsigned*)(ws + 221249536);         // 4
  unsigned short* attnb= qhb;   // qhb dead after k_phiM(q); attnb written by k_cattn
  float*          out  = (float*)d_out;

  hipMemsetAsync(kmax, 0, 4, stream);

  k_transform_b<<<dim3(BHN * LL / 4), dim3(256), 0, stream>>>(queries, Wq, qhb, rsq);
  k_transform_b<<<dim3(BHN * LL / 4), dim3(256), 0, stream>>>(keys,    Wk, khb, rsk);
  k_transform_vT<<<dim3(BHN * (LL / 64)), dim3(256), 0, stream>>>(values, Wv, vTb);
  k_cvtW<<<dim3(512), dim3(256), 0, stream>>>(Wout, Woutb);

  k_phiM<<<dim3(2048), dim3(256), 0, stream>>>(khb, rsk, proj, kmax, nullptr, 0);
  k_phiM<<<dim3(2048), dim3(256), 0, stream>>>(qhb, rsq, proj, kmax, qp, 1);
  k_phiM<<<dim3(2048), dim3(256), 0, stream>>>(khb, rsk, proj, kmax, kp, 2);

  k_chunkKV3<<<dim3(BHN * NCH), dim3(256), 0, stream>>>(kp, vTb, SpT, zfbuf);

  k_prefix_ip<<<dim3((BHN * DD * MM / 8) / 256), dim3(256), 0, stream>>>(SpT);
  k_prefix_z<<<dim3((BHN * MM / 8) / 256), dim3(256), 0, stream>>>(zfbuf, zb);

  k_cattn<<<dim3(BHN * NCH), dim3(256), 0, stream>>>(qp, kp, vTb, SpT, zb, attnb);

  k_proj_M<<<dim3((BB * LL / 64) * (EE / 64)), dim3(256), 0, stream>>>(attnb, Woutb, bout, out);
}

// Round 6
// 450.306 us; speedup vs baseline: 1.8194x; 1.5153x over previous
//
#include <hip/hip_runtime.h>
#include <hip/hip_bf16.h>

// Performer (FAVOR+) causal linear self-attention, MI355X round 5.
// B=4 L=4096 E=512 H=8 D=64 M=256 chunk=128.
// Round 5: never materialize phi(q)/phi(k). Fused MFMA qkv transform; phi(k)
// recomputed inside chunkKV and cattn (LDS-resident); phi(q) fused into cattn.

#define BB 4
#define LL 4096
#define EE 512
#define HH 8
#define DD 64
#define MM 256
#define CC 128
#define NCH 32   // L / CC
#define BHN 32   // B * H

constexpr float DN    = 0.35355339059327373f; // 64^-0.25
constexpr float DIAGC = 0.0625f;              // 0.5 * dn^2
constexpr float RATIO = 0.0625f;              // 256^-0.5
constexpr float EPSV  = 1e-4f;

typedef __attribute__((ext_vector_type(8))) short bf16x8;
typedef __attribute__((ext_vector_type(4))) float f32x4;
union FU { uint4 u; bf16x8 b; };
__device__ __forceinline__ bf16x8 asb(uint4 u){ FU f; f.u = u; return f.b; }
union PK8 { unsigned short s[8]; uint4 u; };

__device__ __forceinline__ unsigned short f2bf(float f){
  unsigned u = __float_as_uint(f);
  u = u + 0x7FFFu + ((u >> 16) & 1u);   // RTNE
  return (unsigned short)(u >> 16);
}
__device__ __forceinline__ float bfl(unsigned u){ return __uint_as_float(u << 16); }
__device__ __forceinline__ unsigned bfpair(float lo, float hi){
  return (unsigned)f2bf(lo) | ((unsigned)f2bf(hi) << 16);
}
__device__ __forceinline__ unsigned enc_f32(float f){
  unsigned u = __float_as_uint(f);
  return (u & 0x80000000u) ? ~u : (u | 0x80000000u);
}
__device__ __forceinline__ float dec_f32(unsigned u){
  unsigned v = (u & 0x80000000u) ? (u & 0x7FFFFFFFu) : ~u;
  return __uint_as_float(v);
}
__device__ __forceinline__ uint4 pack8(float4 a, float4 b){
  PK8 p;
  p.s[0] = f2bf(a.x); p.s[1] = f2bf(a.y); p.s[2] = f2bf(a.z); p.s[3] = f2bf(a.w);
  p.s[4] = f2bf(b.x); p.s[5] = f2bf(b.y); p.s[6] = f2bf(b.z); p.s[7] = f2bf(b.w);
  return p.u;
}

// ---------------- K0a: Wout f32 -> bf16 ----------------
__global__ __launch_bounds__(256) void k_cvtW(const float* __restrict__ W,
                                              unsigned short* __restrict__ Wb){
  int idx = blockIdx.x * 256 + threadIdx.x;
  float2 v = reinterpret_cast<const float2*>(W)[idx];
  reinterpret_cast<unsigned*>(Wb)[idx] = bfpair(v.x, v.y);
}

// ---------------- K0b: proj f32 -> bf16(DN*proj) [256][64] ----------------
__global__ __launch_bounds__(256) void k_cvtP(const float* __restrict__ proj,
                                              unsigned short* __restrict__ projb){
  int idx = blockIdx.x * 256 + threadIdx.x;   // 8192 pairs
  float2 v = reinterpret_cast<const float2*>(proj)[idx];
  reinterpret_cast<unsigned*>(projb)[idx] = bfpair(v.x * DN, v.y * DN);
}

// ---------------- K1: fused MFMA qkv transform ----------------
// q,k: out[l][d] bf16 + rowsum(out^2); v: vT[d][l] bf16 directly.
__global__ __launch_bounds__(256) void k_qkv(const float* __restrict__ xq,
                                             const float* __restrict__ xk,
                                             const float* __restrict__ xv,
                                             const float* __restrict__ Wq,
                                             const float* __restrict__ Wk,
                                             const float* __restrict__ Wv,
                                             unsigned short* __restrict__ qhb,
                                             unsigned short* __restrict__ khb,
                                             unsigned short* __restrict__ vTb,
                                             float* __restrict__ rsq,
                                             float* __restrict__ rsk){
  __shared__ unsigned short Wl[3 * 64 * 64];   // 24KB swizzled bf16
  int tid = threadIdx.x;
  for (int idx = tid; idx < 3 * 64 * 8; idx += 256){
    int sel = idx >> 9, rem = idx & 511, row = rem >> 3, ch = rem & 7;
    const float* Wp = sel == 0 ? Wq : (sel == 1 ? Wk : Wv);
    const float4* w4 = reinterpret_cast<const float4*>(Wp) + row * 16 + ch * 2;
    int byte = sel * 8192 + row * 128 + ((ch * 16) ^ ((row & 7) << 4));
    *reinterpret_cast<uint4*>(reinterpret_cast<char*>(Wl) + byte) = pack8(w4[0], w4[1]);
  }
  __syncthreads();
  int w = tid >> 6, lane = tid & 63, l15 = lane & 15, g = lane >> 4;
  int bh = blockIdx.x >> 5, lb = blockIdx.x & 31;
  int b = bh >> 3, h = bh & 7;
  const char* Wc = reinterpret_cast<const char*>(Wl);
  #pragma unroll
  for (int tt = 0; tt < 2; ++tt){
    int lt = w * 2 + tt;
    int l = lb * 128 + lt * 16 + l15;
    size_t xoff = ((size_t)(b * LL + l)) * EE + h * DD;
    const float4* q4 = reinterpret_cast<const float4*>(xq + xoff);
    const float4* k4 = reinterpret_cast<const float4*>(xk + xoff);
    const float4* v4 = reinterpret_cast<const float4*>(xv + xoff);
    uint4 fq[2], fk[2], fv[2];
    #pragma unroll
    for (int ks = 0; ks < 2; ++ks){
      int fi = ks * 8 + g * 2;
      fq[ks] = pack8(q4[fi], q4[fi + 1]);
      fk[ks] = pack8(k4[fi], k4[fi + 1]);
      fv[ks] = pack8(v4[fi], v4[fi + 1]);
    }
    size_t grow = (size_t)bh * LL + l;
    // ---- q ----
    {
      float ss = 0.f;
      #pragma unroll
      for (int dt = 0; dt < 4; ++dt){
        int row = dt * 16 + l15;
        f32x4 acc = {0.f, 0.f, 0.f, 0.f};
        #pragma unroll
        for (int ks = 0; ks < 2; ++ks){
          int byte = 0 * 8192 + row * 128 + ((ks * 64 + g * 16) ^ ((row & 7) << 4));
          uint4 wf = *reinterpret_cast<const uint4*>(Wc + byte);
          acc = __builtin_amdgcn_mfma_f32_16x16x32_bf16(asb(wf), asb(fq[ks]), acc, 0, 0, 0);
        }
        ss += acc[0]*acc[0] + acc[1]*acc[1] + acc[2]*acc[2] + acc[3]*acc[3];
        ushort4 pk;
        pk.x = f2bf(acc[0]); pk.y = f2bf(acc[1]); pk.z = f2bf(acc[2]); pk.w = f2bf(acc[3]);
        *reinterpret_cast<ushort4*>(qhb + grow * 64 + dt * 16 + g * 4) = pk;
      }
      ss += __shfl_xor(ss, 16, 64);
      ss += __shfl_xor(ss, 32, 64);
      if (g == 0) rsq[grow] = ss;
    }
    // ---- k ----
    {
      float ss = 0.f;
      #pragma unroll
      for (int dt = 0; dt < 4; ++dt){
        int row = dt * 16 + l15;
        f32x4 acc = {0.f, 0.f, 0.f, 0.f};
        #pragma unroll
        for (int ks = 0; ks < 2; ++ks){
          int byte = 1 * 8192 + row * 128 + ((ks * 64 + g * 16) ^ ((row & 7) << 4));
          uint4 wf = *reinterpret_cast<const uint4*>(Wc + byte);
          acc = __builtin_amdgcn_mfma_f32_16x16x32_bf16(asb(wf), asb(fk[ks]), acc, 0, 0, 0);
        }
        ss += acc[0]*acc[0] + acc[1]*acc[1] + acc[2]*acc[2] + acc[3]*acc[3];
        ushort4 pk;
        pk.x = f2bf(acc[0]); pk.y = f2bf(acc[1]); pk.z = f2bf(acc[2]); pk.w = f2bf(acc[3]);
        *reinterpret_cast<ushort4*>(khb + grow * 64 + dt * 16 + g * 4) = pk;
      }
      ss += __shfl_xor(ss, 16, 64);
      ss += __shfl_xor(ss, 32, 64);
      if (g == 0) rsk[grow] = ss;
    }
    // ---- v transposed: D[d][l] = mfma(A=x rows l, B=Wv rows d) ----
    #pragma unroll
    for (int dt = 0; dt < 4; ++dt){
      int row = dt * 16 + l15;
      f32x4 acc = {0.f, 0.f, 0.f, 0.f};
      #pragma unroll
      for (int ks = 0; ks < 2; ++ks){
        int byte = 2 * 8192 + row * 128 + ((ks * 64 + g * 16) ^ ((row & 7) << 4));
        uint4 wf = *reinterpret_cast<const uint4*>(Wc + byte);
        acc = __builtin_amdgcn_mfma_f32_16x16x32_bf16(asb(fv[ks]), asb(wf), acc, 0, 0, 0);
      }
      ushort4 pk;
      pk.x = f2bf(acc[0]); pk.y = f2bf(acc[1]); pk.z = f2bf(acc[2]); pk.w = f2bf(acc[3]);
      *reinterpret_cast<ushort4*>(vTb + ((size_t)(bh * DD + dt * 16 + l15)) * LL
                                  + lb * 128 + lt * 16 + g * 4) = pk;
    }
  }
}

// ---------------- K2: global max of xd(k) via MFMA ----------------
__global__ __launch_bounds__(256) void k_kmaxM(const unsigned short* __restrict__ khb,
                                               const unsigned short* __restrict__ projb,
                                               unsigned* __restrict__ kmaxp){
  int tid = threadIdx.x;
  int w = tid >> 6, lane = tid & 63, l15 = lane & 15, g = lane >> 4;
  int rb = blockIdx.x * 4 + w;
  size_t row = (size_t)rb * 16 + l15;
  const uint4* kh4 = reinterpret_cast<const uint4*>(khb);
  const uint4* pj4 = reinterpret_cast<const uint4*>(projb);
  uint4 kb0 = kh4[row * 8 + g];
  uint4 kb1 = kh4[row * 8 + 4 + g];
  float mx = -3.0e38f;
  #pragma unroll
  for (int mt = 0; mt < 16; ++mt){
    uint4 a0 = pj4[(size_t)(mt * 16 + l15) * 8 + g];
    uint4 a1 = pj4[(size_t)(mt * 16 + l15) * 8 + 4 + g];
    f32x4 acc = {0.f, 0.f, 0.f, 0.f};
    acc = __builtin_amdgcn_mfma_f32_16x16x32_bf16(asb(a0), asb(kb0), acc, 0, 0, 0);
    acc = __builtin_amdgcn_mfma_f32_16x16x32_bf16(asb(a1), asb(kb1), acc, 0, 0, 0);
    mx = fmaxf(mx, fmaxf(fmaxf(acc[0], acc[1]), fmaxf(acc[2], acc[3])));
  }
  #pragma unroll
  for (int off = 32; off >= 1; off >>= 1)
    mx = fmaxf(mx, __shfl_xor(mx, off, 64));
  if (lane == 0) atomicMax(kmaxp, enc_f32(mx));
}

// ---------------- K3: per-chunk KV sums with fused phi(k) ----------------
__global__ __launch_bounds__(256, 2) void k_chunkKV4(const unsigned short* __restrict__ khb,
                                                     const unsigned short* __restrict__ projb,
                                                     const float* __restrict__ rsk,
                                                     const unsigned* __restrict__ kmaxp,
                                                     const unsigned short* __restrict__ vTb,
                                                     unsigned short* __restrict__ SpT,
                                                     float* __restrict__ zf){
  __shared__ unsigned kL[4 * 128 * 33];    // 67.6 KiB, per-wave panels
  int tid = threadIdx.x;
  int w = tid >> 6, lane = tid & 63, l15 = lane & 15, g = lane >> 4;
  int blk = blockIdx.x;
  int bh = blk >> 5, c = blk & 31;
  float km = dec_f32(*kmaxp);
  const uint4* kh4 = reinterpret_cast<const uint4*>(khb);
  const uint4* pj4 = reinterpret_cast<const uint4*>(projb);
  const uint4* vTu = reinterpret_cast<const uint4*>(vTb);
  unsigned* kLw = kL + w * 128 * 33;
  const unsigned short* kL16w = reinterpret_cast<const unsigned short*>(kLw);

  // phi(k) for all 128 j, m-quarter w -> kL panel
  for (int jt = 0; jt < 8; ++jt){
    size_t jrow = (size_t)bh * LL + c * CC + jt * 16 + l15;
    uint4 kb0 = kh4[jrow * 8 + g];
    uint4 kb1 = kh4[jrow * 8 + 4 + g];
    float bs = DIAGC * rsk[jrow] + km;
    #pragma unroll
    for (int mt = 0; mt < 4; ++mt){
      int mrow = w * 64 + mt * 16 + l15;
      uint4 a0 = pj4[(size_t)mrow * 8 + g];
      uint4 a1 = pj4[(size_t)mrow * 8 + 4 + g];
      f32x4 acc = {0.f, 0.f, 0.f, 0.f};
      acc = __builtin_amdgcn_mfma_f32_16x16x32_bf16(asb(a0), asb(kb0), acc, 0, 0, 0);
      acc = __builtin_amdgcn_mfma_f32_16x16x32_bf16(asb(a1), asb(kb1), acc, 0, 0, 0);
      unsigned u0 = bfpair(RATIO * (expf(acc[0] - bs) + EPSV), RATIO * (expf(acc[1] - bs) + EPSV));
      unsigned u1 = bfpair(RATIO * (expf(acc[2] - bs) + EPSV), RATIO * (expf(acc[3] - bs) + EPSV));
      int dwi = (jt * 16 + l15) * 33 + mt * 8 + g * 2;
      kLw[dwi] = u0;
      kLw[dwi + 1] = u1;
    }
  }
  // per-wave panel: compiler inserts lgkm waits for the transposed reads below.

  uint4 vf[4][4];
  #pragma unroll
  for (int dt = 0; dt < 4; ++dt)
    #pragma unroll
    for (int ks = 0; ks < 4; ++ks)
      vf[dt][ks] = vTu[((size_t)(bh * DD + dt * 16 + l15)) * 512 + c * 16 + ks * 4 + g];

  uint4 zero4 = {0u, 0u, 0u, 0u};
  uint4 ones4 = {0x3F803F80u, 0x3F803F80u, 0x3F803F80u, 0x3F803F80u};
  uint4 onesf = (l15 == 0) ? ones4 : zero4;

  #pragma unroll
  for (int mtr = 0; mtr < 4; ++mtr){
    f32x4 acc[4];
    #pragma unroll
    for (int dt = 0; dt < 4; ++dt) acc[dt] = (f32x4){0.f, 0.f, 0.f, 0.f};
    f32x4 accz = {0.f, 0.f, 0.f, 0.f};
    #pragma unroll
    for (int ks = 0; ks < 4; ++ks){
      PK8 p;
      #pragma unroll
      for (int e = 0; e < 8; ++e)
        p.s[e] = kL16w[(ks * 32 + g * 8 + e) * 66 + mtr * 16 + l15];
      bf16x8 kfb = asb(p.u);
      #pragma unroll
      for (int dt = 0; dt < 4; ++dt)
        acc[dt] = __builtin_amdgcn_mfma_f32_16x16x32_bf16(kfb, asb(vf[dt][ks]), acc[dt], 0, 0, 0);
      accz = __builtin_amdgcn_mfma_f32_16x16x32_bf16(kfb, asb(onesf), accz, 0, 0, 0);
    }
    int m0 = w * 64 + mtr * 16;
    #pragma unroll
    for (int dt = 0; dt < 4; ++dt){
      ushort4 pk;
      pk.x = f2bf(acc[dt][0]); pk.y = f2bf(acc[dt][1]);
      pk.z = f2bf(acc[dt][2]); pk.w = f2bf(acc[dt][3]);
      *reinterpret_cast<ushort4*>(SpT + ((size_t)blk * DD + dt * 16 + l15) * MM + m0 + g * 4) = pk;
    }
    if (l15 == 0){
      float4 o; o.x = accz[0]; o.y = accz[1]; o.z = accz[2]; o.w = accz[3];
      *reinterpret_cast<float4*>(zf + (size_t)blk * MM + m0 + g * 4) = o;
    }
  }
}

// ---------------- K4a: in-place exclusive prefix over chunk planes ----------------
__global__ __launch_bounds__(256) void k_prefix_ip(unsigned short* __restrict__ buf){
  const int per8 = (DD * MM) / 8;
  int idx = blockIdx.x * 256 + threadIdx.x;
  int bh = idx / per8, r8 = idx - bh * per8;
  float run[8];
  #pragma unroll
  for (int e = 0; e < 8; ++e) run[e] = 0.f;
  for (int c = 0; c < NCH; ++c){
    size_t a = (((size_t)bh * NCH + c) * (DD * MM)) >> 3;
    uint4* p = reinterpret_cast<uint4*>(buf) + a + r8;
    uint4 v = *p;
    PK8 t; t.u = v;
    PK8 o;
    #pragma unroll
    for (int e = 0; e < 8; ++e){
      o.s[e] = f2bf(run[e]);
      run[e] += bfl((unsigned)t.s[e]);
    }
    *p = o.u;
  }
}

// ---------------- K4b: z prefix f32 -> exclusive bf16 ----------------
__global__ __launch_bounds__(256) void k_prefix_z(const float* __restrict__ zf,
                                                  unsigned short* __restrict__ zb){
  const int per8 = MM / 8;
  int idx = blockIdx.x * 256 + threadIdx.x;
  int bh = idx / per8, r8 = idx - bh * per8;
  float run[8];
  #pragma unroll
  for (int e = 0; e < 8; ++e) run[e] = 0.f;
  for (int c = 0; c < NCH; ++c){
    size_t base = ((size_t)bh * NCH + c) * MM + r8 * 8;
    float4 v0 = *reinterpret_cast<const float4*>(zf + base);
    float4 v1 = *reinterpret_cast<const float4*>(zf + base + 4);
    PK8 o;
    #pragma unroll
    for (int e = 0; e < 8; ++e) o.s[e] = f2bf(run[e]);
    run[0] += v0.x; run[1] += v0.y; run[2] += v0.z; run[3] += v0.w;
    run[4] += v1.x; run[5] += v1.y; run[6] += v1.z; run[7] += v1.w;
    *reinterpret_cast<uint4*>(zb + base) = o.u;
  }
}

// ---------------- K5: chunk causal attention, fused phi(q)+phi(k) ----------------
// LDS: [0,64K) kpL 128x256 bf16 swizzled; [64K,80K) per-wave 16x128 bounce tiles.
__global__ __launch_bounds__(256, 2) void k_cattn5(const unsigned short* __restrict__ qhb,
                                                   const unsigned short* __restrict__ khb,
                                                   const unsigned short* __restrict__ projb,
                                                   const float* __restrict__ rsq,
                                                   const float* __restrict__ rsk,
                                                   const unsigned* __restrict__ kmaxp,
                                                   const unsigned short* __restrict__ vTb,
                                                   const unsigned short* __restrict__ Spb,
                                                   const unsigned short* __restrict__ zb,
                                                   unsigned short* __restrict__ attnb){
  __shared__ unsigned LDSU[20480];   // 80 KiB
  char* lds = reinterpret_cast<char*>(LDSU);
  int tid = threadIdx.x;
  int w = tid >> 6, lane = tid & 63, l15 = lane & 15, g = lane >> 4;
  int blk = blockIdx.x;
  int bh = blk >> 5, c = blk & 31;
  int b = bh >> 3, h = bh & 7;
  size_t grow0 = (size_t)bh * LL + c * CC;
  float km = dec_f32(*kmaxp);
  const uint4* qh4 = reinterpret_cast<const uint4*>(qhb);
  const uint4* kh4 = reinterpret_cast<const uint4*>(khb);
  const uint4* pj4 = reinterpret_cast<const uint4*>(projb);
  const uint4* vTu = reinterpret_cast<const uint4*>(vTb);
  const uint4* Spu = reinterpret_cast<const uint4*>(Spb);
  const uint4* zbu = reinterpret_cast<const uint4*>(zb);

  // ---- cooperative phi(k) -> kpL (wave w does j-tiles w and w+4) ----
  #pragma unroll
  for (int tj = 0; tj < 2; ++tj){
    int jt = w + tj * 4;
    int jr = jt * 16 + l15;
    size_t jrow = grow0 + jr;
    uint4 kb0 = kh4[jrow * 8 + g];
    uint4 kb1 = kh4[jrow * 8 + 4 + g];
    float bs = DIAGC * rsk[jrow] + km;
    #pragma unroll
    for (int mt = 0; mt < 16; ++mt){
      uint4 a0 = pj4[(size_t)(mt * 16 + l15) * 8 + g];
      uint4 a1 = pj4[(size_t)(mt * 16 + l15) * 8 + 4 + g];
      f32x4 acc = {0.f, 0.f, 0.f, 0.f};
      acc = __builtin_amdgcn_mfma_f32_16x16x32_bf16(asb(a0), asb(kb0), acc, 0, 0, 0);
      acc = __builtin_amdgcn_mfma_f32_16x16x32_bf16(asb(a1), asb(kb1), acc, 0, 0, 0);
      uint2 u;
      u.x = bfpair(RATIO * (expf(acc[0] - bs) + EPSV), RATIO * (expf(acc[1] - bs) + EPSV));
      u.y = bfpair(RATIO * (expf(acc[2] - bs) + EPSV), RATIO * (expf(acc[3] - bs) + EPSV));
      int byte = jr * 512 + ((mt * 32 + g * 8) ^ ((jr & 7) << 4));
      *reinterpret_cast<uint2*>(lds + byte) = u;
    }
  }
  __syncthreads();

  uint4 zero4 = {0u, 0u, 0u, 0u};
  uint4 ones4 = {0x3F803F80u, 0x3F803F80u, 0x3F803F80u, 0x3F803F80u};
  int its[2] = { w, 7 - w };
  int swb = 65536 + w * 4096 + l15 * 256;

  for (int t = 0; t < 2; ++t){
    int it = its[t];
    int i = it * 16 + l15;
    size_t irow = grow0 + i;
    // ---- phi(q) ----
    uint4 qb0 = qh4[irow * 8 + g];
    uint4 qb1 = qh4[irow * 8 + 4 + g];
    f32x4 aq[16];
    #pragma unroll
    for (int mt = 0; mt < 16; ++mt){
      uint4 a0 = pj4[(size_t)(mt * 16 + l15) * 8 + g];
      uint4 a1 = pj4[(size_t)(mt * 16 + l15) * 8 + 4 + g];
      f32x4 acc = {0.f, 0.f, 0.f, 0.f};
      acc = __builtin_amdgcn_mfma_f32_16x16x32_bf16(asb(a0), asb(qb0), acc, 0, 0, 0);
      aq[mt] = __builtin_amdgcn_mfma_f32_16x16x32_bf16(asb(a1), asb(qb1), acc, 0, 0, 0);
    }
    float mx = -3.0e38f;
    #pragma unroll
    for (int mt = 0; mt < 16; ++mt)
      mx = fmaxf(mx, fmaxf(fmaxf(aq[mt][0], aq[mt][1]), fmaxf(aq[mt][2], aq[mt][3])));
    mx = fmaxf(mx, __shfl_xor(mx, 16, 64));
    mx = fmaxf(mx, __shfl_xor(mx, 32, 64));
    float bs = DIAGC * rsq[irow] + mx;
    uint4 qf[8];
    #pragma unroll
    for (int half = 0; half < 2; ++half){
      #pragma unroll
      for (int mt = 0; mt < 8; ++mt){
        f32x4 a = aq[half * 8 + mt];
        uint2 u;
        u.x = bfpair(RATIO * (expf(a[0] - bs) + EPSV), RATIO * (expf(a[1] - bs) + EPSV));
        u.y = bfpair(RATIO * (expf(a[2] - bs) + EPSV), RATIO * (expf(a[3] - bs) + EPSV));
        int byte = swb + ((mt * 32 + g * 8) ^ ((l15 & 7) << 4));
        *reinterpret_cast<uint2*>(lds + byte) = u;
      }
      #pragma unroll
      for (int ks = 0; ks < 4; ++ks){
        int byte = swb + ((ks * 64 + g * 16) ^ ((l15 & 7) << 4));
        qf[half * 4 + ks] = *reinterpret_cast<const uint4*>(lds + byte);
      }
    }
    // ---- phase 1: scores from LDS kp ----
    int jtmax = it | 1;
    for (int jt = 0; jt <= jtmax; ++jt){
      f32x4 acc = {0.f, 0.f, 0.f, 0.f};
      int jr = jt * 16 + l15;
      #pragma unroll
      for (int ks = 0; ks < 8; ++ks){
        int byte = jr * 512 + ((ks * 64 + g * 16) ^ ((jr & 7) << 4));
        uint4 kfu = *reinterpret_cast<const uint4*>(lds + byte);
        acc = __builtin_amdgcn_mfma_f32_16x16x32_bf16(asb(kfu), asb(qf[ks]), acc, 0, 0, 0);
      }
      int jb = jt * 16 + g * 4;
      uint2 u;
      u.x = bfpair((jb + 0 <= i) ? acc[0] : 0.f, (jb + 1 <= i) ? acc[1] : 0.f);
      u.y = bfpair((jb + 2 <= i) ? acc[2] : 0.f, (jb + 3 <= i) ? acc[3] : 0.f);
      int byte = swb + ((jt * 32 + g * 8) ^ ((l15 & 7) << 4));
      *reinterpret_cast<uint2*>(lds + byte) = u;
    }
    // ---- phase 2: PV + prefix ----
    f32x4 acc[5];
    #pragma unroll
    for (int a5 = 0; a5 < 5; ++a5) acc[a5] = (f32x4){0.f, 0.f, 0.f, 0.f};
    int ksv = (it >> 1) + 1;
    for (int ks = 0; ks < ksv; ++ks){
      int byte = swb + ((ks * 64 + g * 16) ^ ((l15 & 7) << 4));
      uint4 sfu = *reinterpret_cast<const uint4*>(lds + byte);
      bf16x8 sf = asb(sfu);
      #pragma unroll
      for (int dt = 0; dt < 4; ++dt){
        uint4 vfu = vTu[((size_t)(bh * DD + dt * 16 + l15)) * 512 + c * 16 + ks * 4 + g];
        acc[dt] = __builtin_amdgcn_mfma_f32_16x16x32_bf16(asb(vfu), sf, acc[dt], 0, 0, 0);
      }
      uint4 of = (l15 == 0) ? ones4 : zero4;
      acc[4] = __builtin_amdgcn_mfma_f32_16x16x32_bf16(asb(of), sf, acc[4], 0, 0, 0);
    }
    #pragma unroll
    for (int ks = 0; ks < 8; ++ks){
      bf16x8 qb = asb(qf[ks]);
      #pragma unroll
      for (int dt = 0; dt < 4; ++dt){
        size_t prow = (size_t)blk * DD + dt * 16 + l15;
        acc[dt] = __builtin_amdgcn_mfma_f32_16x16x32_bf16(asb(Spu[prow * 32 + ks * 4 + g]), qb, acc[dt], 0, 0, 0);
      }
      uint4 zfr = (l15 == 0) ? zbu[blk * 32 + ks * 4 + g] : zero4;
      acc[4] = __builtin_amdgcn_mfma_f32_16x16x32_bf16(asb(zfr), qb, acc[4], 0, 0, 0);
    }
    float den = __shfl(acc[4][0], l15, 64);
    float inv = 1.f / den;
    size_t obase = ((size_t)(b * LL + c * CC + i)) * EE + h * DD;
    #pragma unroll
    for (int dt = 0; dt < 4; ++dt){
      ushort4 pk;
      pk.x = f2bf(acc[dt][0] * inv); pk.y = f2bf(acc[dt][1] * inv);
      pk.z = f2bf(acc[dt][2] * inv); pk.w = f2bf(acc[dt][3] * inv);
      *reinterpret_cast<ushort4*>(attnb + obase + dt * 16 + g * 4) = pk;
    }
  }
}

// ---------------- K6: MFMA out-proj: out = attnb @ Woutb^T + bout ----------------
__global__ __launch_bounds__(256) void k_proj_M(const unsigned short* __restrict__ attnb,
                                                const unsigned short* __restrict__ Woutb,
                                                const float* __restrict__ bout,
                                                float* __restrict__ out){
  int tid = threadIdx.x;
  int w = tid >> 6, lane = tid & 63, l15 = lane & 15, g = lane >> 4;
  int rb = blockIdx.x >> 3, eb = blockIdx.x & 7;
  int r0 = rb * 64, e0 = eb * 64;
  int r = r0 + w * 16 + l15;
  const uint4* at4 = reinterpret_cast<const uint4*>(attnb);
  const uint4* Wo4 = reinterpret_cast<const uint4*>(Woutb);
  f32x4 acc[4];
  #pragma unroll
  for (int ct = 0; ct < 4; ++ct) acc[ct] = (f32x4){0.f, 0.f, 0.f, 0.f};
  for (int ks = 0; ks < 16; ++ks){
    uint4 bfrag = at4[((size_t)r * EE + ks * 32 + g * 8) >> 3];
    #pragma unroll
    for (int ct = 0; ct < 4; ++ct){
      uint4 af = Wo4[((size_t)(e0 + ct * 16 + l15) * EE + ks * 32 + g * 8) >> 3];
      acc[ct] = __builtin_amdgcn_mfma_f32_16x16x32_bf16(asb(af), asb(bfrag), acc[ct], 0, 0, 0);
    }
  }
  #pragma unroll
  for (int ct = 0; ct < 4; ++ct){
    int e = e0 + ct * 16 + g * 4;
    float4 bo = *reinterpret_cast<const float4*>(bout + e);
    float4 o;
    o.x = acc[ct][0] + bo.x; o.y = acc[ct][1] + bo.y;
    o.z = acc[ct][2] + bo.z; o.w = acc[ct][3] + bo.w;
    *reinterpret_cast<float4*>(out + (size_t)r * EE + e) = o;
  }
}

extern "C" void kernel_launch(void* const* d_in, const int* in_sizes, int n_in,
                              void* d_out, int out_size, void* d_ws, size_t ws_size,
                              hipStream_t stream){
  const float* queries = (const float*)d_in[0];
  const float* keys    = (const float*)d_in[1];
  const float* values  = (const float*)d_in[2];
  const float* Wq      = (const float*)d_in[3];
  const float* Wk      = (const float*)d_in[4];
  const float* Wv      = (const float*)d_in[5];
  const float* Wout    = (const float*)d_in[6];
  const float* bout    = (const float*)d_in[7];
  const float* proj    = (const float*)d_in[8];

  // workspace layout (~104 MB, no aliasing)
  char* ws = (char*)d_ws;
  unsigned short* qhb  = (unsigned short*)(ws + 0);           // 16.8M [BH,L,D]
  unsigned short* khb  = (unsigned short*)(ws + 16777216);    // 16.8M
  unsigned short* vTb  = (unsigned short*)(ws + 33554432);    // 16.8M [BH,D,L]
  unsigned short* SpT  = (unsigned short*)(ws + 50331648);    // 33.5M [BH,NCH,D,M]
  unsigned short* attnb= (unsigned short*)(ws + 83886080);    // 16.8M [B,L,E]
  float*          zfbuf= (float*)(ws + 100663296);            // 1.0M
  unsigned short* zb   = (unsigned short*)(ws + 101711872);   // 0.5M
  float*          rsq  = (float*)(ws + 102236160);            // 0.5M
  float*          rsk  = (float*)(ws + 102760448);            // 0.5M
  unsigned short* Woutb= (unsigned short*)(ws + 103284736);   // 0.5M
  unsigned short* projb= (unsigned short*)(ws + 103809024);   // 32K  [M,D] bf16 (DN folded)
  unsigned*       kmax = (unsigned*)(ws + 103841792);         // 4
  float*          out  = (float*)d_out;

  hipMemsetAsync(kmax, 0, 4, stream);

  k_cvtW<<<dim3(512), dim3(256), 0, stream>>>(Wout, Woutb);
  k_cvtP<<<dim3(32), dim3(256), 0, stream>>>(proj, projb);

  k_qkv<<<dim3(BHN * 32), dim3(256), 0, stream>>>(queries, keys, values, Wq, Wk, Wv,
                                                  qhb, khb, vTb, rsq, rsk);

  k_kmaxM<<<dim3(2048), dim3(256), 0, stream>>>(khb, projb, kmax);

  k_chunkKV4<<<dim3(BHN * NCH), dim3(256), 0, stream>>>(khb, projb, rsk, kmax, vTb, SpT, zfbuf);

  k_prefix_ip<<<dim3((BHN * DD * MM / 8) / 256), dim3(256), 0, stream>>>(SpT);
  k_prefix_z<<<dim3((BHN * MM / 8) / 256), dim3(256), 0, stream>>>(zfbuf, zb);

  k_cattn5<<<dim3(BHN * NCH), dim3(256), 0, stream>>>(qhb, khb, projb, rsq, rsk, kmax,
                                                      vTb, SpT, zb, attnb);

  k_proj_M<<<dim3((BB * LL / 64) * (EE / 64)), dim3(256), 0, stream>>>(attnb, Woutb, bout, out);
}

// Round 7
// 434.527 us; speedup vs baseline: 1.8855x; 1.0363x over previous
//
#include <hip/hip_runtime.h>
#include <hip/hip_bf16.h>

// Performer (FAVOR+) causal linear self-attention, MI355X round 6.
// B=4 L=4096 E=512 H=8 D=64 M=256 chunk=128.
// Round 6: ILP-restructured cattn (prefix pass hoisted pre-barrier, both
// i-tiles' phi(q) chains interleaved); chunkKV with streamed 4.6KB/wave panel.

#define BB 4
#define LL 4096
#define EE 512
#define HH 8
#define DD 64
#define MM 256
#define CC 128
#define NCH 32   // L / CC
#define BHN 32   // B * H

constexpr float DN    = 0.35355339059327373f; // 64^-0.25
constexpr float DIAGC = 0.0625f;              // 0.5 * dn^2
constexpr float RATIO = 0.0625f;              // 256^-0.5
constexpr float EPSV  = 1e-4f;

typedef __attribute__((ext_vector_type(8))) short bf16x8;
typedef __attribute__((ext_vector_type(4))) float f32x4;
union FU { uint4 u; bf16x8 b; };
__device__ __forceinline__ bf16x8 asb(uint4 u){ FU f; f.u = u; return f.b; }
union PK8 { unsigned short s[8]; uint4 u; };

__device__ __forceinline__ unsigned short f2bf(float f){
  unsigned u = __float_as_uint(f);
  u = u + 0x7FFFu + ((u >> 16) & 1u);   // RTNE
  return (unsigned short)(u >> 16);
}
__device__ __forceinline__ float bfl(unsigned u){ return __uint_as_float(u << 16); }
__device__ __forceinline__ unsigned bfpair(float lo, float hi){
  return (unsigned)f2bf(lo) | ((unsigned)f2bf(hi) << 16);
}
__device__ __forceinline__ unsigned enc_f32(float f){
  unsigned u = __float_as_uint(f);
  return (u & 0x80000000u) ? ~u : (u | 0x80000000u);
}
__device__ __forceinline__ float dec_f32(unsigned u){
  unsigned v = (u & 0x80000000u) ? (u & 0x7FFFFFFFu) : ~u;
  return __uint_as_float(v);
}
__device__ __forceinline__ uint4 pack8(float4 a, float4 b){
  PK8 p;
  p.s[0] = f2bf(a.x); p.s[1] = f2bf(a.y); p.s[2] = f2bf(a.z); p.s[3] = f2bf(a.w);
  p.s[4] = f2bf(b.x); p.s[5] = f2bf(b.y); p.s[6] = f2bf(b.z); p.s[7] = f2bf(b.w);
  return p.u;
}

// ---------------- K0a: Wout f32 -> bf16 ----------------
__global__ __launch_bounds__(256) void k_cvtW(const float* __restrict__ W,
                                              unsigned short* __restrict__ Wb){
  int idx = blockIdx.x * 256 + threadIdx.x;
  float2 v = reinterpret_cast<const float2*>(W)[idx];
  reinterpret_cast<unsigned*>(Wb)[idx] = bfpair(v.x, v.y);
}

// ---------------- K0b: proj f32 -> bf16(DN*proj) [256][64] ----------------
__global__ __launch_bounds__(256) void k_cvtP(const float* __restrict__ proj,
                                              unsigned short* __restrict__ projb){
  int idx = blockIdx.x * 256 + threadIdx.x;   // 8192 pairs
  float2 v = reinterpret_cast<const float2*>(proj)[idx];
  reinterpret_cast<unsigned*>(projb)[idx] = bfpair(v.x * DN, v.y * DN);
}

// ---------------- K1: fused MFMA qkv transform ----------------
__global__ __launch_bounds__(256) void k_qkv(const float* __restrict__ xq,
                                             const float* __restrict__ xk,
                                             const float* __restrict__ xv,
                                             const float* __restrict__ Wq,
                                             const float* __restrict__ Wk,
                                             const float* __restrict__ Wv,
                                             unsigned short* __restrict__ qhb,
                                             unsigned short* __restrict__ khb,
                                             unsigned short* __restrict__ vTb,
                                             float* __restrict__ rsq,
                                             float* __restrict__ rsk){
  __shared__ unsigned short Wl[3 * 64 * 64];   // 24KB swizzled bf16
  int tid = threadIdx.x;
  for (int idx = tid; idx < 3 * 64 * 8; idx += 256){
    int sel = idx >> 9, rem = idx & 511, row = rem >> 3, ch = rem & 7;
    const float* Wp = sel == 0 ? Wq : (sel == 1 ? Wk : Wv);
    const float4* w4 = reinterpret_cast<const float4*>(Wp) + row * 16 + ch * 2;
    int byte = sel * 8192 + row * 128 + ((ch * 16) ^ ((row & 7) << 4));
    *reinterpret_cast<uint4*>(reinterpret_cast<char*>(Wl) + byte) = pack8(w4[0], w4[1]);
  }
  __syncthreads();
  int w = tid >> 6, lane = tid & 63, l15 = lane & 15, g = lane >> 4;
  int bh = blockIdx.x >> 5, lb = blockIdx.x & 31;
  int b = bh >> 3, h = bh & 7;
  const char* Wc = reinterpret_cast<const char*>(Wl);
  #pragma unroll
  for (int tt = 0; tt < 2; ++tt){
    int lt = w * 2 + tt;
    int l = lb * 128 + lt * 16 + l15;
    size_t xoff = ((size_t)(b * LL + l)) * EE + h * DD;
    const float4* q4 = reinterpret_cast<const float4*>(xq + xoff);
    const float4* k4 = reinterpret_cast<const float4*>(xk + xoff);
    const float4* v4 = reinterpret_cast<const float4*>(xv + xoff);
    uint4 fq[2], fk[2], fv[2];
    #pragma unroll
    for (int ks = 0; ks < 2; ++ks){
      int fi = ks * 8 + g * 2;
      fq[ks] = pack8(q4[fi], q4[fi + 1]);
      fk[ks] = pack8(k4[fi], k4[fi + 1]);
      fv[ks] = pack8(v4[fi], v4[fi + 1]);
    }
    size_t grow = (size_t)bh * LL + l;
    // ---- q ----
    {
      float ss = 0.f;
      #pragma unroll
      for (int dt = 0; dt < 4; ++dt){
        int row = dt * 16 + l15;
        f32x4 acc = {0.f, 0.f, 0.f, 0.f};
        #pragma unroll
        for (int ks = 0; ks < 2; ++ks){
          int byte = 0 * 8192 + row * 128 + ((ks * 64 + g * 16) ^ ((row & 7) << 4));
          uint4 wf = *reinterpret_cast<const uint4*>(Wc + byte);
          acc = __builtin_amdgcn_mfma_f32_16x16x32_bf16(asb(wf), asb(fq[ks]), acc, 0, 0, 0);
        }
        ss += acc[0]*acc[0] + acc[1]*acc[1] + acc[2]*acc[2] + acc[3]*acc[3];
        ushort4 pk;
        pk.x = f2bf(acc[0]); pk.y = f2bf(acc[1]); pk.z = f2bf(acc[2]); pk.w = f2bf(acc[3]);
        *reinterpret_cast<ushort4*>(qhb + grow * 64 + dt * 16 + g * 4) = pk;
      }
      ss += __shfl_xor(ss, 16, 64);
      ss += __shfl_xor(ss, 32, 64);
      if (g == 0) rsq[grow] = ss;
    }
    // ---- k ----
    {
      float ss = 0.f;
      #pragma unroll
      for (int dt = 0; dt < 4; ++dt){
        int row = dt * 16 + l15;
        f32x4 acc = {0.f, 0.f, 0.f, 0.f};
        #pragma unroll
        for (int ks = 0; ks < 2; ++ks){
          int byte = 1 * 8192 + row * 128 + ((ks * 64 + g * 16) ^ ((row & 7) << 4));
          uint4 wf = *reinterpret_cast<const uint4*>(Wc + byte);
          acc = __builtin_amdgcn_mfma_f32_16x16x32_bf16(asb(wf), asb(fk[ks]), acc, 0, 0, 0);
        }
        ss += acc[0]*acc[0] + acc[1]*acc[1] + acc[2]*acc[2] + acc[3]*acc[3];
        ushort4 pk;
        pk.x = f2bf(acc[0]); pk.y = f2bf(acc[1]); pk.z = f2bf(acc[2]); pk.w = f2bf(acc[3]);
        *reinterpret_cast<ushort4*>(khb + grow * 64 + dt * 16 + g * 4) = pk;
      }
      ss += __shfl_xor(ss, 16, 64);
      ss += __shfl_xor(ss, 32, 64);
      if (g == 0) rsk[grow] = ss;
    }
    // ---- v transposed ----
    #pragma unroll
    for (int dt = 0; dt < 4; ++dt){
      int row = dt * 16 + l15;
      f32x4 acc = {0.f, 0.f, 0.f, 0.f};
      #pragma unroll
      for (int ks = 0; ks < 2; ++ks){
        int byte = 2 * 8192 + row * 128 + ((ks * 64 + g * 16) ^ ((row & 7) << 4));
        uint4 wf = *reinterpret_cast<const uint4*>(Wc + byte);
        acc = __builtin_amdgcn_mfma_f32_16x16x32_bf16(asb(fv[ks]), asb(wf), acc, 0, 0, 0);
      }
      ushort4 pk;
      pk.x = f2bf(acc[0]); pk.y = f2bf(acc[1]); pk.z = f2bf(acc[2]); pk.w = f2bf(acc[3]);
      *reinterpret_cast<ushort4*>(vTb + ((size_t)(bh * DD + dt * 16 + l15)) * LL
                                  + lb * 128 + lt * 16 + g * 4) = pk;
    }
  }
}

// ---------------- K2: global max of xd(k) via MFMA ----------------
__global__ __launch_bounds__(256) void k_kmaxM(const unsigned short* __restrict__ khb,
                                               const unsigned short* __restrict__ projb,
                                               unsigned* __restrict__ kmaxp){
  int tid = threadIdx.x;
  int w = tid >> 6, lane = tid & 63, l15 = lane & 15, g = lane >> 4;
  int rb = blockIdx.x * 4 + w;
  size_t row = (size_t)rb * 16 + l15;
  const uint4* kh4 = reinterpret_cast<const uint4*>(khb);
  const uint4* pj4 = reinterpret_cast<const uint4*>(projb);
  uint4 kb0 = kh4[row * 8 + g];
  uint4 kb1 = kh4[row * 8 + 4 + g];
  float mx = -3.0e38f;
  #pragma unroll
  for (int mt = 0; mt < 16; ++mt){
    uint4 a0 = pj4[(size_t)(mt * 16 + l15) * 8 + g];
    uint4 a1 = pj4[(size_t)(mt * 16 + l15) * 8 + 4 + g];
    f32x4 acc = {0.f, 0.f, 0.f, 0.f};
    acc = __builtin_amdgcn_mfma_f32_16x16x32_bf16(asb(a0), asb(kb0), acc, 0, 0, 0);
    acc = __builtin_amdgcn_mfma_f32_16x16x32_bf16(asb(a1), asb(kb1), acc, 0, 0, 0);
    mx = fmaxf(mx, fmaxf(fmaxf(acc[0], acc[1]), fmaxf(acc[2], acc[3])));
  }
  #pragma unroll
  for (int off = 32; off >= 1; off >>= 1)
    mx = fmaxf(mx, __shfl_xor(mx, off, 64));
  if (lane == 0) atomicMax(kmaxp, enc_f32(mx));
}

// ---------------- K3: per-chunk KV sums, streamed 16-m panel (4.6KB/wave) ----------------
__global__ __launch_bounds__(256, 4) void k_chunkKV5(const unsigned short* __restrict__ khb,
                                                     const unsigned short* __restrict__ projb,
                                                     const float* __restrict__ rsk,
                                                     const unsigned* __restrict__ kmaxp,
                                                     const unsigned short* __restrict__ vTb,
                                                     unsigned short* __restrict__ SpT,
                                                     float* __restrict__ zf){
  __shared__ unsigned kP[4 * 128 * 9];   // 18,432 B: per-wave [j=128][9 dw] panels
  int tid = threadIdx.x;
  int w = tid >> 6, lane = tid & 63, l15 = lane & 15, g = lane >> 4;
  int blk = blockIdx.x;
  int bh = blk >> 5, c = blk & 31;
  float km = dec_f32(*kmaxp);
  const uint4* kh4 = reinterpret_cast<const uint4*>(khb);
  const uint4* pj4 = reinterpret_cast<const uint4*>(projb);
  const uint4* vTu = reinterpret_cast<const uint4*>(vTb);
  unsigned* pw = kP + w * 128 * 9;
  const unsigned short* p16 = reinterpret_cast<const unsigned short*>(pw);
  uint4 zero4 = {0u, 0u, 0u, 0u};
  uint4 ones4 = {0x3F803F80u, 0x3F803F80u, 0x3F803F80u, 0x3F803F80u};
  uint4 onesf = (l15 == 0) ? ones4 : zero4;

  #pragma unroll
  for (int mtr = 0; mtr < 4; ++mtr){
    int m0 = w * 64 + mtr * 16;
    int mrow = m0 + l15;
    uint4 a0 = pj4[(size_t)mrow * 8 + g];
    uint4 a1 = pj4[(size_t)mrow * 8 + 4 + g];
    // phi(k) slice: all 128 j, 16 m
    #pragma unroll
    for (int jt = 0; jt < 8; ++jt){
      size_t jrow = (size_t)bh * LL + c * CC + jt * 16 + l15;
      uint4 kb0 = kh4[jrow * 8 + g];
      uint4 kb1 = kh4[jrow * 8 + 4 + g];
      float bs = DIAGC * rsk[jrow] + km;
      f32x4 acc = {0.f, 0.f, 0.f, 0.f};
      acc = __builtin_amdgcn_mfma_f32_16x16x32_bf16(asb(a0), asb(kb0), acc, 0, 0, 0);
      acc = __builtin_amdgcn_mfma_f32_16x16x32_bf16(asb(a1), asb(kb1), acc, 0, 0, 0);
      int dwi = (jt * 16 + l15) * 9 + g * 2;
      pw[dwi]     = bfpair(RATIO * (expf(acc[0] - bs) + EPSV), RATIO * (expf(acc[1] - bs) + EPSV));
      pw[dwi + 1] = bfpair(RATIO * (expf(acc[2] - bs) + EPSV), RATIO * (expf(acc[3] - bs) + EPSV));
    }
    // KV MFMAs for this m-slice
    f32x4 acc[4];
    #pragma unroll
    for (int dt = 0; dt < 4; ++dt) acc[dt] = (f32x4){0.f, 0.f, 0.f, 0.f};
    f32x4 accz = {0.f, 0.f, 0.f, 0.f};
    #pragma unroll
    for (int ks = 0; ks < 4; ++ks){
      PK8 p;
      #pragma unroll
      for (int e = 0; e < 8; ++e)
        p.s[e] = p16[(ks * 32 + g * 8 + e) * 18 + l15];
      bf16x8 kfb = asb(p.u);   // A-frag rows m = m0 + l15
      #pragma unroll
      for (int dt = 0; dt < 4; ++dt){
        uint4 vfr = vTu[((size_t)(bh * DD + dt * 16 + l15)) * 512 + c * 16 + ks * 4 + g];
        acc[dt] = __builtin_amdgcn_mfma_f32_16x16x32_bf16(kfb, asb(vfr), acc[dt], 0, 0, 0);
      }
      accz = __builtin_amdgcn_mfma_f32_16x16x32_bf16(kfb, asb(onesf), accz, 0, 0, 0);
    }
    #pragma unroll
    for (int dt = 0; dt < 4; ++dt){
      ushort4 pk;
      pk.x = f2bf(acc[dt][0]); pk.y = f2bf(acc[dt][1]);
      pk.z = f2bf(acc[dt][2]); pk.w = f2bf(acc[dt][3]);
      *reinterpret_cast<ushort4*>(SpT + ((size_t)blk * DD + dt * 16 + l15) * MM + m0 + g * 4) = pk;
    }
    if (l15 == 0){
      float4 o; o.x = accz[0]; o.y = accz[1]; o.z = accz[2]; o.w = accz[3];
      *reinterpret_cast<float4*>(zf + (size_t)blk * MM + m0 + g * 4) = o;
    }
  }
}

// ---------------- K4a: in-place exclusive prefix over chunk planes ----------------
__global__ __launch_bounds__(256) void k_prefix_ip(unsigned short* __restrict__ buf){
  const int per8 = (DD * MM) / 8;
  int idx = blockIdx.x * 256 + threadIdx.x;
  int bh = idx / per8, r8 = idx - bh * per8;
  float run[8];
  #pragma unroll
  for (int e = 0; e < 8; ++e) run[e] = 0.f;
  for (int c = 0; c < NCH; ++c){
    size_t a = (((size_t)bh * NCH + c) * (DD * MM)) >> 3;
    uint4* p = reinterpret_cast<uint4*>(buf) + a + r8;
    uint4 v = *p;
    PK8 t; t.u = v;
    PK8 o;
    #pragma unroll
    for (int e = 0; e < 8; ++e){
      o.s[e] = f2bf(run[e]);
      run[e] += bfl((unsigned)t.s[e]);
    }
    *p = o.u;
  }
}

// ---------------- K4b: z prefix f32 -> exclusive bf16 ----------------
__global__ __launch_bounds__(256) void k_prefix_z(const float* __restrict__ zf,
                                                  unsigned short* __restrict__ zb){
  const int per8 = MM / 8;
  int idx = blockIdx.x * 256 + threadIdx.x;
  int bh = idx / per8, r8 = idx - bh * per8;
  float run[8];
  #pragma unroll
  for (int e = 0; e < 8; ++e) run[e] = 0.f;
  for (int c = 0; c < NCH; ++c){
    size_t base = ((size_t)bh * NCH + c) * MM + r8 * 8;
    float4 v0 = *reinterpret_cast<const float4*>(zf + base);
    float4 v1 = *reinterpret_cast<const float4*>(zf + base + 4);
    PK8 o;
    #pragma unroll
    for (int e = 0; e < 8; ++e) o.s[e] = f2bf(run[e]);
    run[0] += v0.x; run[1] += v0.y; run[2] += v0.z; run[3] += v0.w;
    run[4] += v1.x; run[5] += v1.y; run[6] += v1.z; run[7] += v1.w;
    *reinterpret_cast<uint4*>(zb + base) = o.u;
  }
}

// ---------------- K5: chunk causal attention, ILP-restructured ----------------
// LDS: [0,64K) kpL 128x256 bf16 swizzled; [64K,80K) per-wave 4KB strips.
// Order: phi(k)->kpL | phi(q)+qf+prefix-MFMA for BOTH i-tiles | barrier |
//        scores+PV+out for both i-tiles (fully unrolled, wave-uniform ifs).
__global__ __launch_bounds__(256, 2) void k_cattn6(const unsigned short* __restrict__ qhb,
                                                   const unsigned short* __restrict__ khb,
                                                   const unsigned short* __restrict__ projb,
                                                   const float* __restrict__ rsq,
                                                   const float* __restrict__ rsk,
                                                   const unsigned* __restrict__ kmaxp,
                                                   const unsigned short* __restrict__ vTb,
                                                   const unsigned short* __restrict__ Spb,
                                                   const unsigned short* __restrict__ zb,
                                                   unsigned short* __restrict__ attnb){
  __shared__ unsigned LDSU[20480];   // 80 KiB
  char* lds = reinterpret_cast<char*>(LDSU);
  int tid = threadIdx.x;
  int w = tid >> 6, lane = tid & 63, l15 = lane & 15, g = lane >> 4;
  int blk = blockIdx.x;
  int bh = blk >> 5, c = blk & 31;
  int b = bh >> 3, h = bh & 7;
  size_t grow0 = (size_t)bh * LL + c * CC;
  float km = dec_f32(*kmaxp);
  const uint4* qh4 = reinterpret_cast<const uint4*>(qhb);
  const uint4* kh4 = reinterpret_cast<const uint4*>(khb);
  const uint4* pj4 = reinterpret_cast<const uint4*>(projb);
  const uint4* vTu = reinterpret_cast<const uint4*>(vTb);
  const uint4* Spu = reinterpret_cast<const uint4*>(Spb);
  const uint4* zbu = reinterpret_cast<const uint4*>(zb);
  uint4 zero4 = {0u, 0u, 0u, 0u};
  uint4 ones4 = {0x3F803F80u, 0x3F803F80u, 0x3F803F80u, 0x3F803F80u};

  // ---- A: cooperative phi(k) -> kpL (wave w does j-tiles w and w+4) ----
  #pragma unroll
  for (int tj = 0; tj < 2; ++tj){
    int jt = w + tj * 4;
    int jr = jt * 16 + l15;
    size_t jrow = grow0 + jr;
    uint4 kb0 = kh4[jrow * 8 + g];
    uint4 kb1 = kh4[jrow * 8 + 4 + g];
    float bs = DIAGC * rsk[jrow] + km;
    #pragma unroll
    for (int mt = 0; mt < 16; ++mt){
      uint4 a0 = pj4[(size_t)(mt * 16 + l15) * 8 + g];
      uint4 a1 = pj4[(size_t)(mt * 16 + l15) * 8 + 4 + g];
      f32x4 acc = {0.f, 0.f, 0.f, 0.f};
      acc = __builtin_amdgcn_mfma_f32_16x16x32_bf16(asb(a0), asb(kb0), acc, 0, 0, 0);
      acc = __builtin_amdgcn_mfma_f32_16x16x32_bf16(asb(a1), asb(kb1), acc, 0, 0, 0);
      uint2 u;
      u.x = bfpair(RATIO * (expf(acc[0] - bs) + EPSV), RATIO * (expf(acc[1] - bs) + EPSV));
      u.y = bfpair(RATIO * (expf(acc[2] - bs) + EPSV), RATIO * (expf(acc[3] - bs) + EPSV));
      int byte = jr * 512 + ((mt * 32 + g * 8) ^ ((jr & 7) << 4));
      *reinterpret_cast<uint2*>(lds + byte) = u;
    }
  }

  // ---- B: per-i-tile phi(q) -> qf, plus prefix-state MFMA pass (global) ----
  int its[2] = { w, 7 - w };
  int swb = 65536 + w * 4096 + l15 * 256;
  uint4 qf[2][8];
  f32x4 acc[2][5];
  #pragma unroll
  for (int t = 0; t < 2; ++t)
    #pragma unroll
    for (int a5 = 0; a5 < 5; ++a5) acc[t][a5] = (f32x4){0.f, 0.f, 0.f, 0.f};

  #pragma unroll
  for (int t = 0; t < 2; ++t){
    int i = its[t] * 16 + l15;
    size_t irow = grow0 + i;
    uint4 qb0 = qh4[irow * 8 + g];
    uint4 qb1 = qh4[irow * 8 + 4 + g];
    f32x4 aq[16];
    #pragma unroll
    for (int mt = 0; mt < 16; ++mt){
      uint4 a0 = pj4[(size_t)(mt * 16 + l15) * 8 + g];
      uint4 a1 = pj4[(size_t)(mt * 16 + l15) * 8 + 4 + g];
      f32x4 a = {0.f, 0.f, 0.f, 0.f};
      a = __builtin_amdgcn_mfma_f32_16x16x32_bf16(asb(a0), asb(qb0), a, 0, 0, 0);
      aq[mt] = __builtin_amdgcn_mfma_f32_16x16x32_bf16(asb(a1), asb(qb1), a, 0, 0, 0);
    }
    float mx = -3.0e38f;
    #pragma unroll
    for (int mt = 0; mt < 16; ++mt)
      mx = fmaxf(mx, fmaxf(fmaxf(aq[mt][0], aq[mt][1]), fmaxf(aq[mt][2], aq[mt][3])));
    mx = fmaxf(mx, __shfl_xor(mx, 16, 64));
    mx = fmaxf(mx, __shfl_xor(mx, 32, 64));
    float bs = DIAGC * rsq[irow] + mx;
    #pragma unroll
    for (int half = 0; half < 2; ++half){
      #pragma unroll
      for (int mt = 0; mt < 8; ++mt){
        f32x4 a = aq[half * 8 + mt];
        uint2 u;
        u.x = bfpair(RATIO * (expf(a[0] - bs) + EPSV), RATIO * (expf(a[1] - bs) + EPSV));
        u.y = bfpair(RATIO * (expf(a[2] - bs) + EPSV), RATIO * (expf(a[3] - bs) + EPSV));
        int byte = swb + ((mt * 32 + g * 8) ^ ((l15 & 7) << 4));
        *reinterpret_cast<uint2*>(lds + byte) = u;
      }
      #pragma unroll
      for (int ks = 0; ks < 4; ++ks){
        int byte = swb + ((ks * 64 + g * 16) ^ ((l15 & 7) << 4));
        qf[t][half * 4 + ks] = *reinterpret_cast<const uint4*>(lds + byte);
      }
    }
    // prefix-state pass (global MFMA; latency overlaps A and the other t)
    #pragma unroll
    for (int ks = 0; ks < 8; ++ks){
      bf16x8 qb = asb(qf[t][ks]);
      #pragma unroll
      for (int dt = 0; dt < 4; ++dt){
        size_t prow = (size_t)blk * DD + dt * 16 + l15;
        acc[t][dt] = __builtin_amdgcn_mfma_f32_16x16x32_bf16(asb(Spu[prow * 32 + ks * 4 + g]), qb, acc[t][dt], 0, 0, 0);
      }
      uint4 zfr = (l15 == 0) ? zbu[blk * 32 + ks * 4 + g] : zero4;
      acc[t][4] = __builtin_amdgcn_mfma_f32_16x16x32_bf16(asb(zfr), qb, acc[t][4], 0, 0, 0);
    }
  }
  __syncthreads();

  // ---- C: scores + PV + out, both i-tiles ----
  #pragma unroll
  for (int t = 0; t < 2; ++t){
    int it = its[t];
    int i = it * 16 + l15;
    int jtmax = it | 1;
    #pragma unroll
    for (int jt = 0; jt < 8; ++jt){
      if (jt <= jtmax){   // wave-uniform
        f32x4 sa = {0.f, 0.f, 0.f, 0.f};
        int jr = jt * 16 + l15;
        #pragma unroll
        for (int ks = 0; ks < 8; ++ks){
          int byte = jr * 512 + ((ks * 64 + g * 16) ^ ((jr & 7) << 4));
          uint4 kfu = *reinterpret_cast<const uint4*>(lds + byte);
          sa = __builtin_amdgcn_mfma_f32_16x16x32_bf16(asb(kfu), asb(qf[t][ks]), sa, 0, 0, 0);
        }
        int jb = jt * 16 + g * 4;
        uint2 u;
        u.x = bfpair((jb + 0 <= i) ? sa[0] : 0.f, (jb + 1 <= i) ? sa[1] : 0.f);
        u.y = bfpair((jb + 2 <= i) ? sa[2] : 0.f, (jb + 3 <= i) ? sa[3] : 0.f);
        int byte = swb + ((jt * 32 + g * 8) ^ ((l15 & 7) << 4));
        *reinterpret_cast<uint2*>(lds + byte) = u;
      }
    }
    int ksmax = it >> 1;
    #pragma unroll
    for (int ks = 0; ks < 4; ++ks){
      if (ks <= ksmax){   // wave-uniform
        int byte = swb + ((ks * 64 + g * 16) ^ ((l15 & 7) << 4));
        uint4 sfu = *reinterpret_cast<const uint4*>(lds + byte);
        bf16x8 sf = asb(sfu);
        #pragma unroll
        for (int dt = 0; dt < 4; ++dt){
          uint4 vfu = vTu[((size_t)(bh * DD + dt * 16 + l15)) * 512 + c * 16 + ks * 4 + g];
          acc[t][dt] = __builtin_amdgcn_mfma_f32_16x16x32_bf16(asb(vfu), sf, acc[t][dt], 0, 0, 0);
        }
        uint4 of = (l15 == 0) ? ones4 : zero4;
        acc[t][4] = __builtin_amdgcn_mfma_f32_16x16x32_bf16(asb(of), sf, acc[t][4], 0, 0, 0);
      }
    }
    float den = __shfl(acc[t][4][0], l15, 64);
    float inv = 1.f / den;
    size_t obase = ((size_t)(b * LL + c * CC + i)) * EE + h * DD;
    #pragma unroll
    for (int dt = 0; dt < 4; ++dt){
      ushort4 pk;
      pk.x = f2bf(acc[t][dt][0] * inv); pk.y = f2bf(acc[t][dt][1] * inv);
      pk.z = f2bf(acc[t][dt][2] * inv); pk.w = f2bf(acc[t][dt][3] * inv);
      *reinterpret_cast<ushort4*>(attnb + obase + dt * 16 + g * 4) = pk;
    }
  }
}

// ---------------- K6: MFMA out-proj: out = attnb @ Woutb^T + bout ----------------
__global__ __launch_bounds__(256) void k_proj_M(const unsigned short* __restrict__ attnb,
                                                const unsigned short* __restrict__ Woutb,
                                                const float* __restrict__ bout,
                                                float* __restrict__ out){
  int tid = threadIdx.x;
  int w = tid >> 6, lane = tid & 63, l15 = lane & 15, g = lane >> 4;
  int rb = blockIdx.x >> 3, eb = blockIdx.x & 7;
  int r0 = rb * 64, e0 = eb * 64;
  int r = r0 + w * 16 + l15;
  const uint4* at4 = reinterpret_cast<const uint4*>(attnb);
  const uint4* Wo4 = reinterpret_cast<const uint4*>(Woutb);
  f32x4 acc[4];
  #pragma unroll
  for (int ct = 0; ct < 4; ++ct) acc[ct] = (f32x4){0.f, 0.f, 0.f, 0.f};
  for (int ks = 0; ks < 16; ++ks){
    uint4 bfrag = at4[((size_t)r * EE + ks * 32 + g * 8) >> 3];
    #pragma unroll
    for (int ct = 0; ct < 4; ++ct){
      uint4 af = Wo4[((size_t)(e0 + ct * 16 + l15) * EE + ks * 32 + g * 8) >> 3];
      acc[ct] = __builtin_amdgcn_mfma_f32_16x16x32_bf16(asb(af), asb(bfrag), acc[ct], 0, 0, 0);
    }
  }
  #pragma unroll
  for (int ct = 0; ct < 4; ++ct){
    int e = e0 + ct * 16 + g * 4;
    float4 bo = *reinterpret_cast<const float4*>(bout + e);
    float4 o;
    o.x = acc[ct][0] + bo.x; o.y = acc[ct][1] + bo.y;
    o.z = acc[ct][2] + bo.z; o.w = acc[ct][3] + bo.w;
    *reinterpret_cast<float4*>(out + (size_t)r * EE + e) = o;
  }
}

extern "C" void kernel_launch(void* const* d_in, const int* in_sizes, int n_in,
                              void* d_out, int out_size, void* d_ws, size_t ws_size,
                              hipStream_t stream){
  const float* queries = (const float*)d_in[0];
  const float* keys    = (const float*)d_in[1];
  const float* values  = (const float*)d_in[2];
  const float* Wq      = (const float*)d_in[3];
  const float* Wk      = (const float*)d_in[4];
  const float* Wv      = (const float*)d_in[5];
  const float* Wout    = (const float*)d_in[6];
  const float* bout    = (const float*)d_in[7];
  const float* proj    = (const float*)d_in[8];

  // workspace layout (~104 MB, no aliasing)
  char* ws = (char*)d_ws;
  unsigned short* qhb  = (unsigned short*)(ws + 0);           // 16.8M [BH,L,D]
  unsigned short* khb  = (unsigned short*)(ws + 16777216);    // 16.8M
  unsigned short* vTb  = (unsigned short*)(ws + 33554432);    // 16.8M [BH,D,L]
  unsigned short* SpT  = (unsigned short*)(ws + 50331648);    // 33.5M [BH,NCH,D,M]
  unsigned short* attnb= (unsigned short*)(ws + 83886080);    // 16.8M [B,L,E]
  float*          zfbuf= (float*)(ws + 100663296);            // 1.0M
  unsigned short* zb   = (unsigned short*)(ws + 101711872);   // 0.5M
  float*          rsq  = (float*)(ws + 102236160);            // 0.5M
  float*          rsk  = (float*)(ws + 102760448);            // 0.5M
  unsigned short* Woutb= (unsigned short*)(ws + 103284736);   // 0.5M
  unsigned short* projb= (unsigned short*)(ws + 103809024);   // 32K  [M,D] bf16 (DN folded)
  unsigned*       kmax = (unsigned*)(ws + 103841792);         // 4
  float*          out  = (float*)d_out;

  hipMemsetAsync(kmax, 0, 4, stream);

  k_cvtW<<<dim3(512), dim3(256), 0, stream>>>(Wout, Woutb);
  k_cvtP<<<dim3(32), dim3(256), 0, stream>>>(proj, projb);

  k_qkv<<<dim3(BHN * 32), dim3(256), 0, stream>>>(queries, keys, values, Wq, Wk, Wv,
                                                  qhb, khb, vTb, rsq, rsk);

  k_kmaxM<<<dim3(2048), dim3(256), 0, stream>>>(khb, projb, kmax);

  k_chunkKV5<<<dim3(BHN * NCH), dim3(256), 0, stream>>>(khb, projb, rsk, kmax, vTb, SpT, zfbuf);

  k_prefix_ip<<<dim3((BHN * DD * MM / 8) / 256), dim3(256), 0, stream>>>(SpT);
  k_prefix_z<<<dim3((BHN * MM / 8) / 256), dim3(256), 0, stream>>>(zfbuf, zb);

  k_cattn6<<<dim3(BHN * NCH), dim3(256), 0, stream>>>(qhb, khb, projb, rsq, rsk, kmax,
                                                      vTb, SpT, zb, attnb);

  k_proj_M<<<dim3((BB * LL / 64) * (EE / 64)), dim3(256), 0, stream>>>(attnb, Woutb, bout, out);
}